// Round 4
// baseline (530.903 us; speedup 1.0000x reference)
//
#include <hip/hip_runtime.h>

#define T_STEPS 48
#define BATCH   48
#define DG      256
#define DH      512
#define S_INNER 3
#define HDSTRIDE 258   // histd row stride in u32 (256 data + 2 pad) -> 2-way max conflicts
#define HPSTRIDE 26    // histpT row stride in u32 (24 data + 2 pad)

typedef _Float16 hf2 __attribute__((ext_vector_type(2)));

__device__ __forceinline__ hf2 bch(unsigned u) { return __builtin_bit_cast(hf2, u); }
__device__ __forceinline__ unsigned pkh(_Float16 a, _Float16 b) {
  hf2 v{a, b}; return __builtin_bit_cast(unsigned, v);
}
__device__ __forceinline__ float fdot2u(unsigned a, unsigned b, float c) {
#if __has_builtin(__builtin_amdgcn_fdot2)
  return __builtin_amdgcn_fdot2(bch(a), bch(b), c, false);
#else
  hf2 x = bch(a), y = bch(b);
  return fmaf((float)x.x, (float)y.x, fmaf((float)x.y, (float)y.y, c));
#endif
}
__device__ __forceinline__ float wave_reduce_sum(float v) {
  #pragma unroll
  for (int off = 32; off > 0; off >>= 1) v += __shfl_xor(v, off, 64);
  return v;
}
template <int CTRL>
__device__ __forceinline__ float dpp_add(float v) {
  int t = __builtin_amdgcn_update_dpp(0, __float_as_int(v), CTRL, 0xf, 0xf, true);
  return v + __int_as_float(t);
}
// full 64-lane sum using VALU DPP for 4 levels (xor1,2,7,15) + 2 shuffles (16,32)
__device__ __forceinline__ float wave64_sum_fast(float v) {
  v = dpp_add<0xB1>(v);    // quad_perm [1,0,3,2]  == xor1
  v = dpp_add<0x4E>(v);    // quad_perm [2,3,0,1]  == xor2
  v = dpp_add<0x141>(v);   // row_half_mirror      == xor7
  v = dpp_add<0x140>(v);   // row_mirror           == xor15
  v += __shfl_xor(v, 16, 64);
  v += __shfl_xor(v, 32, 64);
  return v;
}

// ---------- weight packing: Whq[j*128 + q] = 4 dims {4q..4q+3} of column j, fp16
__global__ __launch_bounds__(256)
void pack_whq(const float* __restrict__ W, uint2* __restrict__ Wq) {
  int idx = blockIdx.x * 256 + threadIdx.x;   // 65536
  int j = idx & (DH - 1), q = idx >> 9;
  float w0 = W[(size_t)(4 * q + 0) * DH + j];
  float w1 = W[(size_t)(4 * q + 1) * DH + j];
  float w2 = W[(size_t)(4 * q + 2) * DH + j];
  float w3 = W[(size_t)(4 * q + 3) * DH + j];
  uint2 o;
  o.x = pkh((_Float16)w0, (_Float16)w1);
  o.y = pkh((_Float16)w2, (_Float16)w3);
  Wq[(size_t)j * 128 + q] = o;
}

__global__ __launch_bounds__(256)
void transpose_k(const float* __restrict__ in, float* __restrict__ out, int R, int C) {
  __shared__ float tile[32][33];
  int c0 = blockIdx.x * 32, r0 = blockIdx.y * 32;
  int tx = threadIdx.x & 31, ty = threadIdx.x >> 5;
  #pragma unroll
  for (int k = 0; k < 32; k += 8)
    tile[ty + k][tx] = in[(size_t)(r0 + ty + k) * C + (c0 + tx)];
  __syncthreads();
  #pragma unroll
  for (int k = 0; k < 32; k += 8)
    out[(size_t)(c0 + ty + k) * R + (r0 + tx)] = tile[tx][ty + k];
}

__global__ __launch_bounds__(DH, 2)
void zg_kernel(const float* __restrict__ z, const float* __restrict__ WgT,
               float* __restrict__ ZG) {
  const int row0 = blockIdx.x * 8;
  const int tid = threadIdx.x;
  __shared__ __align__(16) float zl[8][DG];
  for (int i = tid; i < 8 * (DG / 4); i += DH) {
    int r = i >> 6, c = i & 63;
    ((float4*)zl[r])[c] = ((const float4*)(z + (size_t)(row0 + r) * DG))[c];
  }
  __syncthreads();
  float acc[8] = {0.f, 0.f, 0.f, 0.f, 0.f, 0.f, 0.f, 0.f};
  for (int j = 0; j < DG; j += 4) {
    float w0 = WgT[(size_t)(j + 0) * DH + tid];
    float w1 = WgT[(size_t)(j + 1) * DH + tid];
    float w2 = WgT[(size_t)(j + 2) * DH + tid];
    float w3 = WgT[(size_t)(j + 3) * DH + tid];
    #pragma unroll
    for (int r = 0; r < 8; ++r) {
      float4 zz = ((const float4*)zl[r])[j >> 2];
      acc[r] = fmaf(w0, zz.x, acc[r]);
      acc[r] = fmaf(w1, zz.y, acc[r]);
      acc[r] = fmaf(w2, zz.z, acc[r]);
      acc[r] = fmaf(w3, zz.w, acc[r]);
    }
  }
  #pragma unroll
  for (int r = 0; r < 8; ++r)
    ZG[(size_t)(row0 + r) * DH + tid] = acc[r];
}

__global__ __launch_bounds__(1024, 4)
void rnn_main(const float* __restrict__ ZG, const uint2* __restrict__ Whq,
              const float* __restrict__ bh, const float* __restrict__ gamma,
              const float* __restrict__ beta, const float* __restrict__ W_head,
              const float* __restrict__ b_head, const float* __restrict__ clean,
              float* __restrict__ outbuf) {
  const int b = blockIdx.x;
  const int tid  = threadIdx.x;         // 1024 threads = 16 waves
  const int lane = tid & 63;
  const int wv   = tid >> 6;            // 0..15
  const int dim  = tid & (DH - 1);      // owner dim (lower half)
  const bool lower = tid < DH;          // wave-uniform
  const int q     = tid & 127;          // quad index 0..127 (matvec)
  const int slice = tid >> 7;           // 0..7 split-K slice (matvec)

  __shared__ __align__(16) unsigned histd[T_STEPS * HDSTRIDE];  // 49.5KB dim-pair history
  __shared__ __align__(16) unsigned histpT[DH * HPSTRIDE];      // 53.2KB s-pair transposed
  __shared__ __align__(16) float    pm[8 * DH];                 // 16KB split-K partials
  __shared__ __align__(16) uint2    AP[DH + 32];                // active list {j*128, h2}
  __shared__ __align__(16) unsigned h2cur[256];                 // current h, dim-pairs fp16
  __shared__ __align__(16) unsigned cbufh2[32];                 // c coeffs, s-pairs fp16
  __shared__ __align__(16) float    hcur[DH];
  __shared__ __align__(16) float    pred[DG];
  __shared__ float2 red[8];
  __shared__ float  red4[64];
  __shared__ int    wcnt[8];
  __shared__ float  lampow[T_STEPS];

  float g_i = 0.f, be_i = 0.f, bh_i = 0.f;
  if (lower) { g_i = gamma[dim]; be_i = beta[dim]; bh_i = bh[dim]; }
  if (tid == 0) {
    float pw = 0.5f;                    // eta folded in
    for (int k = 0; k < T_STEPS; ++k) { lampow[k] = pw; pw *= 0.95f; }
  }
  for (int i = tid; i < DH * HPSTRIDE; i += 1024) histpT[i] = 0u;  // NaN-safety for x0 reads
  __syncthreads();

  int cntp = 0;    // padded active count (multiple of 32), uniform

  for (int t = 0; t < T_STEPS; ++t) {
    float zg = lower ? ZG[((size_t)t * BATCH + b) * DH + dim] : 0.f;

    // prefetch this step's histpT row (static within the step; overlaps matvec)
    uint2 pf[12];
    if (lower && t > 0) {
      const uint2* rp = (const uint2*)(histpT + dim * HPSTRIDE);
      #pragma unroll
      for (int k = 0; k < 12; ++k) pf[k] = rp[k];
    } else {
      #pragma unroll
      for (int k = 0; k < 12; ++k) { pf[k].x = 0u; pf[k].y = 0u; }
    }

    // ---- matvec: pm[slice][4q..4q+3] += W_h h_prev over this slice's actives
    {
      hf2 ma0{}, ma1{}, mc0{}, mc1{};
      const int n = cntp >> 3;          // per-slice entries, multiple of 4
      if (t > 0 && n > 0) {
        int e = slice;
        uint2 p0 = AP[e], p1 = AP[e + 8], p2 = AP[e + 16], p3 = AP[e + 24];
        uint2 w0 = Whq[p0.x + q], w1 = Whq[p1.x + q];
        uint2 w2 = Whq[p2.x + q], w3 = Whq[p3.x + q];
        for (int m = 4; m < n; m += 4) {
          e += 32;
          uint2 q0 = AP[e], q1 = AP[e + 8], q2 = AP[e + 16], q3 = AP[e + 24];
          uint2 v0 = Whq[q0.x + q], v1 = Whq[q1.x + q];
          uint2 v2 = Whq[q2.x + q], v3 = Whq[q3.x + q];
          ma0 += bch(w0.x) * bch(p0.y); mc0 += bch(w0.y) * bch(p0.y);
          ma1 += bch(w1.x) * bch(p1.y); mc1 += bch(w1.y) * bch(p1.y);
          ma0 += bch(w2.x) * bch(p2.y); mc0 += bch(w2.y) * bch(p2.y);
          ma1 += bch(w3.x) * bch(p3.y); mc1 += bch(w3.y) * bch(p3.y);
          p0 = q0; p1 = q1; p2 = q2; p3 = q3;
          w0 = v0; w1 = v1; w2 = v2; w3 = v3;
        }
        ma0 += bch(w0.x) * bch(p0.y); mc0 += bch(w0.y) * bch(p0.y);
        ma1 += bch(w1.x) * bch(p1.y); mc1 += bch(w1.y) * bch(p1.y);
        ma0 += bch(w2.x) * bch(p2.y); mc0 += bch(w2.y) * bch(p2.y);
        ma1 += bch(w3.x) * bch(p3.y); mc1 += bch(w3.y) * bch(p3.y);
      }
      float4 s4;
      s4.x = (float)ma0.x + (float)ma1.x; s4.y = (float)ma0.y + (float)ma1.y;
      s4.z = (float)mc0.x + (float)mc1.x; s4.w = (float)mc0.y + (float)mc1.y;
      ((float4*)(pm + slice * DH))[q] = s4;
    }
    __syncthreads();                                     // B-mv

    float base_i = 0.f;
    if (lower) {
      base_i = bh_i + zg;
      if (t > 0) {
        float ps = 0.f;
        #pragma unroll
        for (int sl = 0; sl < 8; ++sl) ps += pm[sl * DH + dim];
        base_i += ps;
      }
    }

    // ---- inner settling
    for (int inr = 0; inr <= S_INNER; ++inr) {
      float x = 0.f, sa = 0.f, sb = 0.f;
      if (lower) {
        float Ah = 0.f;
        if (inr > 0 && t > 0) {
          const uint4* cbp = (const uint4*)cbufh2;
          uint4 c0 = cbp[0], c1 = cbp[1], c2 = cbp[2];
          uint4 c3 = cbp[3], c4 = cbp[4], c5 = cbp[5];
          float A0 = 0.f, A1 = 0.f, A2 = 0.f, A3 = 0.f;
          A0 = fdot2u(pf[0].x,  c0.x, A0); A1 = fdot2u(pf[0].y,  c0.y, A1);
          A2 = fdot2u(pf[1].x,  c0.z, A2); A3 = fdot2u(pf[1].y,  c0.w, A3);
          A0 = fdot2u(pf[2].x,  c1.x, A0); A1 = fdot2u(pf[2].y,  c1.y, A1);
          A2 = fdot2u(pf[3].x,  c1.z, A2); A3 = fdot2u(pf[3].y,  c1.w, A3);
          A0 = fdot2u(pf[4].x,  c2.x, A0); A1 = fdot2u(pf[4].y,  c2.y, A1);
          A2 = fdot2u(pf[5].x,  c2.z, A2); A3 = fdot2u(pf[5].y,  c2.w, A3);
          A0 = fdot2u(pf[6].x,  c3.x, A0); A1 = fdot2u(pf[6].y,  c3.y, A1);
          A2 = fdot2u(pf[7].x,  c3.z, A2); A3 = fdot2u(pf[7].y,  c3.w, A3);
          A0 = fdot2u(pf[8].x,  c4.x, A0); A1 = fdot2u(pf[8].y,  c4.y, A1);
          A2 = fdot2u(pf[9].x,  c4.z, A2); A3 = fdot2u(pf[9].y,  c4.w, A3);
          A0 = fdot2u(pf[10].x, c5.x, A0); A1 = fdot2u(pf[10].y, c5.y, A1);
          A2 = fdot2u(pf[11].x, c5.z, A2); A3 = fdot2u(pf[11].y, c5.w, A3);
          Ah = (A0 + A1) + (A2 + A3);
        }
        x = base_i + Ah;
        sa = wave64_sum_fast(x);
        sb = wave64_sum_fast(x * x);
        if (lane == 0) red[wv] = make_float2(sa, sb);
      }
      __syncthreads();                                   // B1
      float h = 0.f;
      if (lower) {
        float s = 0.f, s2 = 0.f;
        #pragma unroll
        for (int w = 0; w < 8; ++w) { float2 r = red[w]; s += r.x; s2 += r.y; }
        const float inv = 1.f / (float)DH;
        float mu  = s * inv;
        float var = s2 * inv - mu * mu;
        float rstd = rsqrtf(var + 1e-5f);
        h = fmaxf(fmaf((x - mu) * rstd, g_i, be_i), 0.f);
      }

      if (inr < S_INNER) {
        if (lower) {
          float hn = __shfl_xor(h, 1, 64);
          if ((dim & 1) == 0) h2cur[dim >> 1] = pkh((_Float16)h, (_Float16)hn);
        }
        __syncthreads();                                 // B2
        if (wv == 8) {
          // shuffle-free dots: lane = s, in-lane fdot2 over full dim range
          float a0 = 0.f, a1 = 0.f, a2 = 0.f, a3 = 0.f;
          if (lane < t) {
            const unsigned* rowp = histd + lane * HDSTRIDE;
            #pragma unroll 4
            for (int c = 0; c < 16; ++c) {
              const uint2* rp2 = (const uint2*)(rowp + c * 16);
              const uint4* hc4 = (const uint4*)(h2cur + c * 16);
              uint2 u0 = rp2[0], u1 = rp2[1], u2 = rp2[2], u3 = rp2[3];
              uint2 u4 = rp2[4], u5 = rp2[5], u6 = rp2[6], u7 = rp2[7];
              uint4 v0 = hc4[0], v1 = hc4[1], v2 = hc4[2], v3 = hc4[3];
              a0 = fdot2u(u0.x, v0.x, a0); a1 = fdot2u(u0.y, v0.y, a1);
              a2 = fdot2u(u1.x, v0.z, a2); a3 = fdot2u(u1.y, v0.w, a3);
              a0 = fdot2u(u2.x, v1.x, a0); a1 = fdot2u(u2.y, v1.y, a1);
              a2 = fdot2u(u3.x, v1.z, a2); a3 = fdot2u(u3.y, v1.w, a3);
              a0 = fdot2u(u4.x, v2.x, a0); a1 = fdot2u(u4.y, v2.y, a1);
              a2 = fdot2u(u5.x, v2.z, a2); a3 = fdot2u(u5.y, v2.w, a3);
              a0 = fdot2u(u6.x, v3.x, a0); a1 = fdot2u(u6.y, v3.y, a1);
              a2 = fdot2u(u7.x, v3.z, a2); a3 = fdot2u(u7.y, v3.w, a3);
            }
          }
          float cc = 0.f;
          if (lane < t) cc = ((a0 + a1) + (a2 + a3)) * lampow[t - 1 - lane];
          if (lane < 52) {
            _Float16 ch = (_Float16)cc;
            ((unsigned short*)cbufh2)[lane] = __builtin_bit_cast(unsigned short, ch);
          }
        }
        __syncthreads();                                 // B3
      } else {
        // final inner: publish history + build active list
        unsigned long long mb = 0ull; int myoff = 0;
        if (lower) {
          unsigned short hb = __builtin_bit_cast(unsigned short, (_Float16)h);
          float hn = __shfl_xor(h, 1, 64);
          if ((dim & 1) == 0)
            histd[t * HDSTRIDE + (dim >> 1)] = pkh((_Float16)h, (_Float16)hn);
          ((unsigned short*)(histpT + dim * HPSTRIDE + (t >> 1)))[t & 1] = hb;
          if (t == T_STEPS - 1) hcur[dim] = h;
          mb = __ballot(h != 0.f);
          myoff = __popcll(mb & ((1ull << lane) - 1ull));
          if (lane == 0) wcnt[wv] = __popcll(mb);
        }
        __syncthreads();                                 // B4
        int cnt = 0, wbase = 0;
        #pragma unroll
        for (int w = 0; w < 8; ++w) {
          int c = wcnt[w];
          if (w < wv) wbase += c;
          cnt += c;
        }
        if (lower && h != 0.f) {
          _Float16 hh = (_Float16)h;
          uint2 ent; ent.x = (unsigned)(dim << 7); ent.y = pkh(hh, hh);
          AP[wbase + myoff] = ent;
        }
        cntp = (cnt + 31) & ~31;
        if (tid < cntp - cnt) { uint2 zz; zz.x = 0u; zz.y = 0u; AP[cnt + tid] = zz; }
        __syncthreads();                                 // B5
      }
    }
  }

  // ---- epilogue: pred = h @ W_head^T + b_head, then loss/acc
  for (int r = wv; r < DG; r += 16) {
    const float4* w4  = (const float4*)(W_head + (size_t)r * DH);
    const float4* hc4 = (const float4*)hcur;
    float pdot = 0.f;
    #pragma unroll
    for (int kk = 0; kk < 2; ++kk) {
      float4 a4 = w4[lane + 64 * kk];
      float4 c4 = hc4[lane + 64 * kk];
      pdot += a4.x * c4.x + a4.y * c4.y + a4.z * c4.z + a4.w * c4.w;
    }
    pdot = wave_reduce_sum(pdot);
    if (lane == 0) pred[r] = pdot + b_head[r];
  }
  __syncthreads();

  float sq = 0.f, pc = 0.f, pp = 0.f, cc = 0.f;
  if (tid < DG) {
    float pv = pred[tid];
    float cv = clean[(size_t)b * DG + tid];
    float d = pv - cv;
    sq = d * d; pc = pv * cv; pp = pv * pv; cc = cv * cv;
  }
  #pragma unroll
  for (int off = 32; off > 0; off >>= 1) {
    sq += __shfl_xor(sq, off, 64);
    pc += __shfl_xor(pc, off, 64);
    pp += __shfl_xor(pp, off, 64);
    cc += __shfl_xor(cc, off, 64);
  }
  if (lane == 0) {
    red4[wv * 4 + 0] = sq; red4[wv * 4 + 1] = pc;
    red4[wv * 4 + 2] = pp; red4[wv * 4 + 3] = cc;
  }
  __syncthreads();
  if (tid == 0) {
    float Sq = 0.f, Pc = 0.f, Pp = 0.f, Cc = 0.f;
    #pragma unroll
    for (int w = 0; w < 16; ++w) {
      Sq += red4[w * 4 + 0]; Pc += red4[w * 4 + 1];
      Pp += red4[w * 4 + 2]; Cc += red4[w * 4 + 3];
    }
    outbuf[b]         = Sq / (Cc + 1e-6f);
    outbuf[BATCH + b] = Pc / ((sqrtf(Pp) + 1e-6f) * (sqrtf(Cc) + 1e-6f));
  }
}

__global__ __launch_bounds__(64)
void finalize_k(const float* __restrict__ outbuf, float* __restrict__ out) {
  int tid = threadIdx.x;
  float l = (tid < BATCH) ? outbuf[tid] : 0.f;
  float a = (tid < BATCH) ? outbuf[BATCH + tid] : 0.f;
  #pragma unroll
  for (int off = 32; off > 0; off >>= 1) {
    l += __shfl_xor(l, off, 64);
    a += __shfl_xor(a, off, 64);
  }
  if (tid == 0) {
    out[0] = l * (1.f / (float)BATCH);
    out[1] = a * (1.f / (float)BATCH);
  }
}

extern "C" void kernel_launch(void* const* d_in, const int* in_sizes, int n_in,
                              void* d_out, int out_size, void* d_ws, size_t ws_size,
                              hipStream_t stream) {
  (void)in_sizes; (void)n_in; (void)out_size; (void)ws_size;
  const float* z      = (const float*)d_in[0];
  const float* clean  = (const float*)d_in[1];
  const float* W_h    = (const float*)d_in[2];
  const float* W_g    = (const float*)d_in[3];
  const float* b_h    = (const float*)d_in[4];
  const float* gamma  = (const float*)d_in[5];
  const float* beta   = (const float*)d_in[6];
  const float* W_head = (const float*)d_in[7];
  const float* b_head = (const float*)d_in[8];

  float* wsf     = (float*)d_ws;
  uint2* Whq     = (uint2*)wsf;                           // 65536 uint2 = 131072 f32 slots
  float* WgT     = wsf + 131072;                          // 256*512
  float* ZG      = WgT + (size_t)DG * DH;                 // 2304*512
  float* outbuf  = ZG + (size_t)T_STEPS * BATCH * DH;     // 96

  hipLaunchKernelGGL(pack_whq, dim3(256), dim3(256), 0, stream, W_h, Whq);
  hipLaunchKernelGGL(transpose_k, dim3(DG / 32, DH / 32), dim3(256), 0, stream,
                     W_g, WgT, DH, DG);
  hipLaunchKernelGGL(zg_kernel, dim3((T_STEPS * BATCH) / 8), dim3(DH), 0, stream,
                     z, WgT, ZG);
  hipLaunchKernelGGL(rnn_main, dim3(BATCH), dim3(1024), 0, stream,
                     ZG, Whq, b_h, gamma, beta, W_head, b_head, clean, outbuf);
  hipLaunchKernelGGL(finalize_k, dim3(1), dim3(64), 0, stream,
                     outbuf, (float*)d_out);
}

// Round 5
// 388.086 us; speedup vs baseline: 1.3680x; 1.3680x over previous
//
#include <hip/hip_runtime.h>

#define T_STEPS 48
#define BATCH   48
#define DG      256
#define DH      512
#define S_INNER 3
#define HDSTRIDE 260   // histd row stride in u32 (256 data + 4 pad): 16B-aligned rows

typedef _Float16 hf2 __attribute__((ext_vector_type(2)));

__device__ __forceinline__ hf2 bch(unsigned u) { return __builtin_bit_cast(hf2, u); }
__device__ __forceinline__ unsigned pkh(_Float16 a, _Float16 b) {
  hf2 v{a, b}; return __builtin_bit_cast(unsigned, v);
}
__device__ __forceinline__ float fdot2u(unsigned a, unsigned b, float c) {
#if __has_builtin(__builtin_amdgcn_fdot2)
  return __builtin_amdgcn_fdot2(bch(a), bch(b), c, false);
#else
  hf2 x = bch(a), y = bch(b);
  return fmaf((float)x.x, (float)y.x, fmaf((float)x.y, (float)y.y, c));
#endif
}
__device__ __forceinline__ _Float16 lnr(float x, float mu, float rstd, float g, float be) {
  return (_Float16)fmaxf(fmaf((x - mu) * rstd, g, be), 0.f);
}
__device__ __forceinline__ float wave_reduce_sum(float v) {
  #pragma unroll
  for (int off = 32; off > 0; off >>= 1) v += __shfl_xor(v, off, 64);
  return v;
}
template <int CTRL>
__device__ __forceinline__ float dpp_add(float v) {
  int t = __builtin_amdgcn_update_dpp(0, __float_as_int(v), CTRL, 0xf, 0xf, true);
  return v + __int_as_float(t);
}
// full 64-lane sum: 4 DPP (xor1,2,7,15) + 2 cross-lane shuffles (16,32)
__device__ __forceinline__ float wave64_sum_fast(float v) {
  v = dpp_add<0xB1>(v);    // quad_perm xor1
  v = dpp_add<0x4E>(v);    // quad_perm xor2
  v = dpp_add<0x141>(v);   // row_half_mirror == xor7
  v = dpp_add<0x140>(v);   // row_mirror      == xor15
  v += __shfl_xor(v, 16, 64);
  v += __shfl_xor(v, 32, 64);
  return v;
}

// ---------- weight packing: Whq[j*128 + q] = 4 dims {4q..4q+3} of column j, fp16
__global__ __launch_bounds__(256)
void pack_whq(const float* __restrict__ W, uint2* __restrict__ Wq) {
  int idx = blockIdx.x * 256 + threadIdx.x;   // 65536
  int j = idx & (DH - 1), q = idx >> 9;
  float w0 = W[(size_t)(4 * q + 0) * DH + j];
  float w1 = W[(size_t)(4 * q + 1) * DH + j];
  float w2 = W[(size_t)(4 * q + 2) * DH + j];
  float w3 = W[(size_t)(4 * q + 3) * DH + j];
  uint2 o;
  o.x = pkh((_Float16)w0, (_Float16)w1);
  o.y = pkh((_Float16)w2, (_Float16)w3);
  Wq[(size_t)j * 128 + q] = o;
}

__global__ __launch_bounds__(256)
void transpose_k(const float* __restrict__ in, float* __restrict__ out, int R, int C) {
  __shared__ float tile[32][33];
  int c0 = blockIdx.x * 32, r0 = blockIdx.y * 32;
  int tx = threadIdx.x & 31, ty = threadIdx.x >> 5;
  #pragma unroll
  for (int k = 0; k < 32; k += 8)
    tile[ty + k][tx] = in[(size_t)(r0 + ty + k) * C + (c0 + tx)];
  __syncthreads();
  #pragma unroll
  for (int k = 0; k < 32; k += 8)
    out[(size_t)(c0 + ty + k) * R + (r0 + tx)] = tile[tx][ty + k];
}

__global__ __launch_bounds__(DH, 2)
void zg_kernel(const float* __restrict__ z, const float* __restrict__ WgT,
               float* __restrict__ ZG) {
  const int row0 = blockIdx.x * 8;
  const int tid = threadIdx.x;
  __shared__ __align__(16) float zl[8][DG];
  for (int i = tid; i < 8 * (DG / 4); i += DH) {
    int r = i >> 6, c = i & 63;
    ((float4*)zl[r])[c] = ((const float4*)(z + (size_t)(row0 + r) * DG))[c];
  }
  __syncthreads();
  float acc[8] = {0.f, 0.f, 0.f, 0.f, 0.f, 0.f, 0.f, 0.f};
  for (int j = 0; j < DG; j += 4) {
    float w0 = WgT[(size_t)(j + 0) * DH + tid];
    float w1 = WgT[(size_t)(j + 1) * DH + tid];
    float w2 = WgT[(size_t)(j + 2) * DH + tid];
    float w3 = WgT[(size_t)(j + 3) * DH + tid];
    #pragma unroll
    for (int r = 0; r < 8; ++r) {
      float4 zz = ((const float4*)zl[r])[j >> 2];
      acc[r] = fmaf(w0, zz.x, acc[r]);
      acc[r] = fmaf(w1, zz.y, acc[r]);
      acc[r] = fmaf(w2, zz.z, acc[r]);
      acc[r] = fmaf(w3, zz.w, acc[r]);
    }
  }
  #pragma unroll
  for (int r = 0; r < 8; ++r)
    ZG[(size_t)(row0 + r) * DH + tid] = acc[r];
}

#define HCASE(s) case (2*(s)): hreg[(s)] = hb; break; \
                 case (2*(s)+1): hreg[(s)] |= (hb << 16); break;

__global__ __launch_bounds__(1024, 4)
void rnn_main(const float* __restrict__ ZG, const uint2* __restrict__ Whq,
              const float* __restrict__ bh, const float* __restrict__ gamma,
              const float* __restrict__ beta, const float* __restrict__ W_head,
              const float* __restrict__ b_head, const float* __restrict__ clean,
              float* __restrict__ outbuf) {
  const int b = blockIdx.x;
  const int tid  = threadIdx.x;         // 1024 threads = 16 waves
  const int lane = tid & 63;
  const int wv   = tid >> 6;            // 0..15
  const int dim  = tid & (DH - 1);      // owner dim (lower half)
  const bool lower = tid < DH;          // wave-uniform
  const int q     = tid & 127;          // quad index 0..127 (matvec)
  const int slice = tid >> 7;           // 0..7 split-K slice (matvec)

  __shared__ __align__(16) unsigned histd[T_STEPS * HDSTRIDE];  // 49.9KB dim-pair history
  __shared__ __align__(16) float    pm[8 * DH];                 // 16KB split-K partials
  __shared__ __align__(16) float    xbuf[DH];                   // pre-LN x publish
  __shared__ __align__(16) uint2    AP[DH + 32];                // active list {j*128, h2}
  __shared__ __align__(16) unsigned cbufh2[24];                 // c coeffs, s-pairs fp16
  __shared__ __align__(16) float    hcur[DH];
  __shared__ __align__(16) float    pred[DG];
  __shared__ float2 red[8];
  __shared__ float  red4[64];
  __shared__ int    wcnt[8];
  __shared__ float  lampow[T_STEPS];

  float g_i = 0.f, be_i = 0.f, bh_i = 0.f;
  if (lower) { g_i = gamma[dim]; be_i = beta[dim]; bh_i = bh[dim]; }
  // per-lane 8-dim gamma/beta for the dot-phase h recompute (dims 8*lane..8*lane+7)
  float4 gA = ((const float4*)gamma)[2 * lane], gB = ((const float4*)gamma)[2 * lane + 1];
  float4 bA = ((const float4*)beta)[2 * lane],  bB = ((const float4*)beta)[2 * lane + 1];
  if (tid == 0) {
    float pw = 0.5f;                    // eta folded in
    for (int k = 0; k < T_STEPS; ++k) { lampow[k] = pw; pw *= 0.95f; }
  }
  unsigned hreg[24];                    // this owner's fp16 history column, s-pairs
  #pragma unroll
  for (int k = 0; k < 24; ++k) hreg[k] = 0u;
  __syncthreads();

  int cntp = 0;    // padded active count (multiple of 32), uniform

  for (int t = 0; t < T_STEPS; ++t) {
    float zg = lower ? ZG[((size_t)t * BATCH + b) * DH + dim] : 0.f;

    // prefetch this step's 3 dot rows (histd static within a step; rows >= t unused)
    uint4 rowv[3];
    #pragma unroll
    for (int k = 0; k < 3; ++k)
      rowv[k] = *(const uint4*)(histd + (wv + 16 * k) * HDSTRIDE + 4 * lane);

    // ---- matvec: pm[slice][4q..4q+3] += W_h h_prev over this slice's actives
    {
      hf2 ma0{}, ma1{}, mc0{}, mc1{};
      const int n = cntp >> 3;          // per-slice entries, multiple of 4
      if (t > 0 && n > 0) {
        int e = slice;
        uint2 p0 = AP[e], p1 = AP[e + 8], p2 = AP[e + 16], p3 = AP[e + 24];
        uint2 w0 = Whq[p0.x + q], w1 = Whq[p1.x + q];
        uint2 w2 = Whq[p2.x + q], w3 = Whq[p3.x + q];
        for (int m = 4; m < n; m += 4) {
          e += 32;
          uint2 q0 = AP[e], q1 = AP[e + 8], q2 = AP[e + 16], q3 = AP[e + 24];
          uint2 v0 = Whq[q0.x + q], v1 = Whq[q1.x + q];
          uint2 v2 = Whq[q2.x + q], v3 = Whq[q3.x + q];
          ma0 += bch(w0.x) * bch(p0.y); mc0 += bch(w0.y) * bch(p0.y);
          ma1 += bch(w1.x) * bch(p1.y); mc1 += bch(w1.y) * bch(p1.y);
          ma0 += bch(w2.x) * bch(p2.y); mc0 += bch(w2.y) * bch(p2.y);
          ma1 += bch(w3.x) * bch(p3.y); mc1 += bch(w3.y) * bch(p3.y);
          p0 = q0; p1 = q1; p2 = q2; p3 = q3;
          w0 = v0; w1 = v1; w2 = v2; w3 = v3;
        }
        ma0 += bch(w0.x) * bch(p0.y); mc0 += bch(w0.y) * bch(p0.y);
        ma1 += bch(w1.x) * bch(p1.y); mc1 += bch(w1.y) * bch(p1.y);
        ma0 += bch(w2.x) * bch(p2.y); mc0 += bch(w2.y) * bch(p2.y);
        ma1 += bch(w3.x) * bch(p3.y); mc1 += bch(w3.y) * bch(p3.y);
      }
      float4 s4;
      s4.x = (float)ma0.x + (float)ma1.x; s4.y = (float)ma0.y + (float)ma1.y;
      s4.z = (float)mc0.x + (float)mc1.x; s4.w = (float)mc0.y + (float)mc1.y;
      ((float4*)(pm + slice * DH))[q] = s4;
    }
    __syncthreads();                                     // B-mv

    float base_i = 0.f;
    if (lower) {
      base_i = bh_i + zg;
      if (t > 0) {
        float ps = 0.f;
        #pragma unroll
        for (int sl = 0; sl < 8; ++sl) ps += pm[sl * DH + dim];
        base_i += ps;
      }
    }

    // ---- inner settling: 2 barriers per inner
    for (int inr = 0; inr <= S_INNER; ++inr) {
      float x = 0.f;
      if (lower) {
        float Ah = 0.f;
        if (inr > 0 && t > 0) {
          unsigned cw[24];
          const uint4* cbp = (const uint4*)cbufh2;
          #pragma unroll
          for (int k = 0; k < 6; ++k) {
            uint4 v = cbp[k];
            cw[4 * k] = v.x; cw[4 * k + 1] = v.y; cw[4 * k + 2] = v.z; cw[4 * k + 3] = v.w;
          }
          float A0 = 0.f, A1 = 0.f, A2 = 0.f, A3 = 0.f;
          #pragma unroll
          for (int sp = 0; sp < 24; sp += 4) {
            A0 = fdot2u(hreg[sp + 0], cw[sp + 0], A0);
            A1 = fdot2u(hreg[sp + 1], cw[sp + 1], A1);
            A2 = fdot2u(hreg[sp + 2], cw[sp + 2], A2);
            A3 = fdot2u(hreg[sp + 3], cw[sp + 3], A3);
          }
          Ah = (A0 + A1) + (A2 + A3);
        }
        x = base_i + Ah;
        xbuf[dim] = x;
        float sa = wave64_sum_fast(x);
        float sb = wave64_sum_fast(x * x);
        if (lane == 0) red[wv] = make_float2(sa, sb);
      }
      __syncthreads();                                   // B1
      float mu, rstd;
      {
        float s = 0.f, s2 = 0.f;
        #pragma unroll
        for (int w = 0; w < 8; ++w) { float2 r = red[w]; s += r.x; s2 += r.y; }
        const float inv = 1.f / (float)DH;
        mu = s * inv;
        float var = s2 * inv - mu * mu;
        rstd = rsqrtf(var + 1e-5f);
      }

      if (inr < S_INNER) {
        // all 16 waves: recompute h for dims 8*lane..8*lane+7, dot vs 3 rows
        float4 xa = ((const float4*)xbuf)[2 * lane];
        float4 xb = ((const float4*)xbuf)[2 * lane + 1];
        uint4 hcv;
        hcv.x = pkh(lnr(xa.x, mu, rstd, gA.x, bA.x), lnr(xa.y, mu, rstd, gA.y, bA.y));
        hcv.y = pkh(lnr(xa.z, mu, rstd, gA.z, bA.z), lnr(xa.w, mu, rstd, gA.w, bA.w));
        hcv.z = pkh(lnr(xb.x, mu, rstd, gB.x, bB.x), lnr(xb.y, mu, rstd, gB.y, bB.y));
        hcv.w = pkh(lnr(xb.z, mu, rstd, gB.z, bB.z), lnr(xb.w, mu, rstd, gB.w, bB.w));
        #pragma unroll
        for (int k = 0; k < 3; ++k) {
          int r = wv + 16 * k;
          float pd = fdot2u(rowv[k].x, hcv.x,
                     fdot2u(rowv[k].y, hcv.y,
                     fdot2u(rowv[k].z, hcv.z,
                     fdot2u(rowv[k].w, hcv.w, 0.f))));
          pd = wave64_sum_fast(pd);
          float cc = (r < t) ? pd * lampow[t - 1 - r] : 0.f;
          if (lane == 0) {
            _Float16 ch = (_Float16)cc;
            ((unsigned short*)cbufh2)[r] = __builtin_bit_cast(unsigned short, ch);
          }
        }
        __syncthreads();                                 // B2
      } else {
        // final inner: owners materialize h, publish history, build active list
        float h = 0.f;
        unsigned long long mb = 0ull; int myoff = 0;
        if (lower) {
          h = fmaxf(fmaf((x - mu) * rstd, g_i, be_i), 0.f);
          unsigned hb = (unsigned)__builtin_bit_cast(unsigned short, (_Float16)h);
          float hn = __shfl_xor(h, 1, 64);
          if ((dim & 1) == 0)
            histd[t * HDSTRIDE + (dim >> 1)] = pkh((_Float16)h, (_Float16)hn);
          switch (t) {
            HCASE(0)  HCASE(1)  HCASE(2)  HCASE(3)  HCASE(4)  HCASE(5)
            HCASE(6)  HCASE(7)  HCASE(8)  HCASE(9)  HCASE(10) HCASE(11)
            HCASE(12) HCASE(13) HCASE(14) HCASE(15) HCASE(16) HCASE(17)
            HCASE(18) HCASE(19) HCASE(20) HCASE(21) HCASE(22) HCASE(23)
          }
          if (t == T_STEPS - 1) hcur[dim] = h;
          mb = __ballot(h != 0.f);
          myoff = __popcll(mb & ((1ull << lane) - 1ull));
          if (lane == 0) wcnt[wv] = __popcll(mb);
        }
        __syncthreads();                                 // B4
        int cnt = 0, wbase = 0;
        #pragma unroll
        for (int w = 0; w < 8; ++w) {
          int c = wcnt[w];
          if (w < wv) wbase += c;
          cnt += c;
        }
        if (lower && h != 0.f) {
          _Float16 hh = (_Float16)h;
          uint2 ent; ent.x = (unsigned)(dim << 7); ent.y = pkh(hh, hh);
          AP[wbase + myoff] = ent;
        }
        cntp = (cnt + 31) & ~31;
        if (tid < cntp - cnt) { uint2 zz; zz.x = 0u; zz.y = 0u; AP[cnt + tid] = zz; }
        __syncthreads();                                 // B5
      }
    }
  }

  // ---- epilogue: pred = h @ W_head^T + b_head, then loss/acc
  for (int r = wv; r < DG; r += 16) {
    const float4* w4  = (const float4*)(W_head + (size_t)r * DH);
    const float4* hc4 = (const float4*)hcur;
    float pdot = 0.f;
    #pragma unroll
    for (int kk = 0; kk < 2; ++kk) {
      float4 a4 = w4[lane + 64 * kk];
      float4 c4 = hc4[lane + 64 * kk];
      pdot += a4.x * c4.x + a4.y * c4.y + a4.z * c4.z + a4.w * c4.w;
    }
    pdot = wave_reduce_sum(pdot);
    if (lane == 0) pred[r] = pdot + b_head[r];
  }
  __syncthreads();

  float sq = 0.f, pc = 0.f, pp = 0.f, cc = 0.f;
  if (tid < DG) {
    float pv = pred[tid];
    float cv = clean[(size_t)b * DG + tid];
    float d = pv - cv;
    sq = d * d; pc = pv * cv; pp = pv * pv; cc = cv * cv;
  }
  #pragma unroll
  for (int off = 32; off > 0; off >>= 1) {
    sq += __shfl_xor(sq, off, 64);
    pc += __shfl_xor(pc, off, 64);
    pp += __shfl_xor(pp, off, 64);
    cc += __shfl_xor(cc, off, 64);
  }
  if (lane == 0) {
    red4[wv * 4 + 0] = sq; red4[wv * 4 + 1] = pc;
    red4[wv * 4 + 2] = pp; red4[wv * 4 + 3] = cc;
  }
  __syncthreads();
  if (tid == 0) {
    float Sq = 0.f, Pc = 0.f, Pp = 0.f, Cc = 0.f;
    #pragma unroll
    for (int w = 0; w < 16; ++w) {
      Sq += red4[w * 4 + 0]; Pc += red4[w * 4 + 1];
      Pp += red4[w * 4 + 2]; Cc += red4[w * 4 + 3];
    }
    outbuf[b]         = Sq / (Cc + 1e-6f);
    outbuf[BATCH + b] = Pc / ((sqrtf(Pp) + 1e-6f) * (sqrtf(Cc) + 1e-6f));
  }
}

__global__ __launch_bounds__(64)
void finalize_k(const float* __restrict__ outbuf, float* __restrict__ out) {
  int tid = threadIdx.x;
  float l = (tid < BATCH) ? outbuf[tid] : 0.f;
  float a = (tid < BATCH) ? outbuf[BATCH + tid] : 0.f;
  #pragma unroll
  for (int off = 32; off > 0; off >>= 1) {
    l += __shfl_xor(l, off, 64);
    a += __shfl_xor(a, off, 64);
  }
  if (tid == 0) {
    out[0] = l * (1.f / (float)BATCH);
    out[1] = a * (1.f / (float)BATCH);
  }
}

extern "C" void kernel_launch(void* const* d_in, const int* in_sizes, int n_in,
                              void* d_out, int out_size, void* d_ws, size_t ws_size,
                              hipStream_t stream) {
  (void)in_sizes; (void)n_in; (void)out_size; (void)ws_size;
  const float* z      = (const float*)d_in[0];
  const float* clean  = (const float*)d_in[1];
  const float* W_h    = (const float*)d_in[2];
  const float* W_g    = (const float*)d_in[3];
  const float* b_h    = (const float*)d_in[4];
  const float* gamma  = (const float*)d_in[5];
  const float* beta   = (const float*)d_in[6];
  const float* W_head = (const float*)d_in[7];
  const float* b_head = (const float*)d_in[8];

  float* wsf     = (float*)d_ws;
  uint2* Whq     = (uint2*)wsf;                           // 65536 uint2 = 131072 f32 slots
  float* WgT     = wsf + 131072;                          // 256*512
  float* ZG      = WgT + (size_t)DG * DH;                 // 2304*512
  float* outbuf  = ZG + (size_t)T_STEPS * BATCH * DH;     // 96

  hipLaunchKernelGGL(pack_whq, dim3(256), dim3(256), 0, stream, W_h, Whq);
  hipLaunchKernelGGL(transpose_k, dim3(DG / 32, DH / 32), dim3(256), 0, stream,
                     W_g, WgT, DH, DG);
  hipLaunchKernelGGL(zg_kernel, dim3((T_STEPS * BATCH) / 8), dim3(DH), 0, stream,
                     z, WgT, ZG);
  hipLaunchKernelGGL(rnn_main, dim3(BATCH), dim3(1024), 0, stream,
                     ZG, Whq, b_h, gamma, beta, W_head, b_head, clean, outbuf);
  hipLaunchKernelGGL(finalize_k, dim3(1), dim3(64), 0, stream,
                     outbuf, (float*)d_out);
}

// Round 6
// 346.926 us; speedup vs baseline: 1.5303x; 1.1186x over previous
//
#include <hip/hip_runtime.h>

#define T_STEPS 48
#define BATCH   48
#define DG      256
#define DH      512
#define S_INNER 3
#define HDSTRIDE 260   // histd row stride in u32: +4-bank skew per row, 16B-aligned

typedef _Float16 hf2 __attribute__((ext_vector_type(2)));

__device__ __forceinline__ hf2 bch(unsigned u) { return __builtin_bit_cast(hf2, u); }
__device__ __forceinline__ unsigned pkh(_Float16 a, _Float16 b) {
  hf2 v{a, b}; return __builtin_bit_cast(unsigned, v);
}
__device__ __forceinline__ float fdot2u(unsigned a, unsigned b, float c) {
#if __has_builtin(__builtin_amdgcn_fdot2)
  return __builtin_amdgcn_fdot2(bch(a), bch(b), c, false);
#else
  hf2 x = bch(a), y = bch(b);
  return fmaf((float)x.x, (float)y.x, fmaf((float)x.y, (float)y.y, c));
#endif
}
__device__ __forceinline__ float wave_reduce_sum(float v) {
  #pragma unroll
  for (int off = 32; off > 0; off >>= 1) v += __shfl_xor(v, off, 64);
  return v;
}
template <int CTRL>
__device__ __forceinline__ float dpp_add(float v) {
  int t = __builtin_amdgcn_update_dpp(0, __float_as_int(v), CTRL, 0xf, 0xf, true);
  return v + __int_as_float(t);
}
template <int CTRL>
__device__ __forceinline__ float dpp_mov(float v) {
  return __int_as_float(
      __builtin_amdgcn_update_dpp(0, __float_as_int(v), CTRL, 0xf, 0xf, true));
}
// 64-lane sum, result valid in lane 63; zero LDS traffic
__device__ __forceinline__ float wave64_sum63(float v) {
  v = dpp_add<0xB1>(v);    // xor1 (quad_perm)
  v = dpp_add<0x4E>(v);    // xor2 (quad_perm)
  v = dpp_add<0x141>(v);   // row_half_mirror
  v = dpp_add<0x140>(v);   // row_mirror -> 16-row sums in all lanes
  v = dpp_add<0x142>(v);   // row_bcast15
  v = dpp_add<0x143>(v);   // row_bcast31 -> total in lanes 48..63
  return v;
}
// sum over each 16-lane row, result in all 16 lanes of the row
__device__ __forceinline__ float row16_sum(float v) {
  v = dpp_add<0xB1>(v);
  v = dpp_add<0x4E>(v);
  v = dpp_add<0x141>(v);
  v = dpp_add<0x140>(v);
  return v;
}

// ---------- weight packing: Whq[j*128 + q] = 4 dims {4q..4q+3} of column j, fp16
__global__ __launch_bounds__(256)
void pack_whq(const float* __restrict__ W, uint2* __restrict__ Wq) {
  int idx = blockIdx.x * 256 + threadIdx.x;   // 65536
  int j = idx & (DH - 1), q = idx >> 9;
  float w0 = W[(size_t)(4 * q + 0) * DH + j];
  float w1 = W[(size_t)(4 * q + 1) * DH + j];
  float w2 = W[(size_t)(4 * q + 2) * DH + j];
  float w3 = W[(size_t)(4 * q + 3) * DH + j];
  uint2 o;
  o.x = pkh((_Float16)w0, (_Float16)w1);
  o.y = pkh((_Float16)w2, (_Float16)w3);
  Wq[(size_t)j * 128 + q] = o;
}

__global__ __launch_bounds__(256)
void transpose_k(const float* __restrict__ in, float* __restrict__ out, int R, int C) {
  __shared__ float tile[32][33];
  int c0 = blockIdx.x * 32, r0 = blockIdx.y * 32;
  int tx = threadIdx.x & 31, ty = threadIdx.x >> 5;
  #pragma unroll
  for (int k = 0; k < 32; k += 8)
    tile[ty + k][tx] = in[(size_t)(r0 + ty + k) * C + (c0 + tx)];
  __syncthreads();
  #pragma unroll
  for (int k = 0; k < 32; k += 8)
    out[(size_t)(c0 + ty + k) * R + (r0 + tx)] = tile[tx][ty + k];
}

__global__ __launch_bounds__(DH, 2)
void zg_kernel(const float* __restrict__ z, const float* __restrict__ WgT,
               float* __restrict__ ZG) {
  const int row0 = blockIdx.x * 8;
  const int tid = threadIdx.x;
  __shared__ __align__(16) float zl[8][DG];
  for (int i = tid; i < 8 * (DG / 4); i += DH) {
    int r = i >> 6, c = i & 63;
    ((float4*)zl[r])[c] = ((const float4*)(z + (size_t)(row0 + r) * DG))[c];
  }
  __syncthreads();
  float acc[8] = {0.f, 0.f, 0.f, 0.f, 0.f, 0.f, 0.f, 0.f};
  for (int j = 0; j < DG; j += 4) {
    float w0 = WgT[(size_t)(j + 0) * DH + tid];
    float w1 = WgT[(size_t)(j + 1) * DH + tid];
    float w2 = WgT[(size_t)(j + 2) * DH + tid];
    float w3 = WgT[(size_t)(j + 3) * DH + tid];
    #pragma unroll
    for (int r = 0; r < 8; ++r) {
      float4 zz = ((const float4*)zl[r])[j >> 2];
      acc[r] = fmaf(w0, zz.x, acc[r]);
      acc[r] = fmaf(w1, zz.y, acc[r]);
      acc[r] = fmaf(w2, zz.z, acc[r]);
      acc[r] = fmaf(w3, zz.w, acc[r]);
    }
  }
  #pragma unroll
  for (int r = 0; r < 8; ++r)
    ZG[(size_t)(row0 + r) * DH + tid] = acc[r];
}

#define HCASE(s) case (2*(s)): hreg[(s)] = hb; break; \
                 case (2*(s)+1): hreg[(s)] |= (hb << 16); break;

__global__ __launch_bounds__(1024, 4)
void rnn_main(const float* __restrict__ ZG, const uint2* __restrict__ Whq,
              const float* __restrict__ bh, const float* __restrict__ gamma,
              const float* __restrict__ beta, const float* __restrict__ W_head,
              const float* __restrict__ b_head, const float* __restrict__ clean,
              float* __restrict__ outbuf) {
  const int b = blockIdx.x;
  const int tid  = threadIdx.x;         // 1024 threads = 16 waves
  const int lane = tid & 63;
  const int wv   = tid >> 6;            // 0..15
  const int dim  = tid;                 // owner dim (tid < 512)
  const bool lower = tid < DH;          // waves 0..7: owners
  const int q     = tid & 127;          // matvec quad index
  const int slice = tid >> 7;           // matvec split-K slice 0..7
  const bool isdot = tid < 768;         // waves 0..11: dot engines
  const int dst = tid >> 4;             // dot row s (0..47)
  const int dj  = tid & 15;             // dot col group (32 dims)

  __shared__ __align__(16) unsigned histd[T_STEPS * HDSTRIDE];  // fp16 dim-pair history
  __shared__ __align__(16) float    pm[8 * DH];                 // split-K partials
  __shared__ __align__(16) uint2    AP[DH + 32];                // active list {j*128, h2}
  __shared__ __align__(16) unsigned h2cur[256];                 // current h, dim-pairs
  __shared__ __align__(16) unsigned cbufh2[24];                 // c coeffs (48 fp16)
  __shared__ __align__(16) float    hcur[DH];
  __shared__ __align__(16) float    pred[DG];
  __shared__ float2 red[8];
  __shared__ float  red4[64];
  __shared__ int    wcnt[8];
  __shared__ float  lampow[T_STEPS];

  float g_i = 0.f, be_i = 0.f, bh_i = 0.f;
  if (lower) { g_i = gamma[dim]; be_i = beta[dim]; bh_i = bh[dim]; }
  if (tid == 0) {
    float pw = 0.5f;                    // eta folded in
    for (int k = 0; k < T_STEPS; ++k) { lampow[k] = pw; pw *= 0.95f; }
  }
  unsigned hreg[24];                    // owner's fp16 history column, s-pairs
  #pragma unroll
  for (int k = 0; k < 24; ++k) hreg[k] = 0u;
  __syncthreads();

  int cntp = 0;    // padded active count (multiple of 32), uniform

  for (int t = 0; t < T_STEPS; ++t) {
    float zg = lower ? ZG[((size_t)t * BATCH + b) * DH + dim] : 0.f;

    // per-step prefetch: dot thread's 32-dim segment of hist row dst (static in step)
    uint4 hr0, hr1, hr2, hr3;
    if (isdot) {
      const unsigned* rp = histd + dst * HDSTRIDE + 16 * dj;
      hr0 = *(const uint4*)(rp + 0);
      hr1 = *(const uint4*)(rp + 4);
      hr2 = *(const uint4*)(rp + 8);
      hr3 = *(const uint4*)(rp + 12);
    } else {
      hr0 = hr1 = hr2 = hr3 = make_uint4(0u, 0u, 0u, 0u);
    }

    // ---- matvec: pm[slice][4q..4q+3] += W_h h_prev over this slice's actives
    {
      hf2 ma0{}, ma1{}, mc0{}, mc1{};
      const int n = cntp >> 3;          // per-slice entries, multiple of 4
      if (t > 0 && n > 0) {
        int e = slice;
        uint2 p0 = AP[e], p1 = AP[e + 8], p2 = AP[e + 16], p3 = AP[e + 24];
        uint2 w0 = Whq[p0.x + q], w1 = Whq[p1.x + q];
        uint2 w2 = Whq[p2.x + q], w3 = Whq[p3.x + q];
        for (int m = 4; m < n; m += 4) {
          e += 32;
          uint2 q0 = AP[e], q1 = AP[e + 8], q2 = AP[e + 16], q3 = AP[e + 24];
          uint2 v0 = Whq[q0.x + q], v1 = Whq[q1.x + q];
          uint2 v2 = Whq[q2.x + q], v3 = Whq[q3.x + q];
          ma0 += bch(w0.x) * bch(p0.y); mc0 += bch(w0.y) * bch(p0.y);
          ma1 += bch(w1.x) * bch(p1.y); mc1 += bch(w1.y) * bch(p1.y);
          ma0 += bch(w2.x) * bch(p2.y); mc0 += bch(w2.y) * bch(p2.y);
          ma1 += bch(w3.x) * bch(p3.y); mc1 += bch(w3.y) * bch(p3.y);
          p0 = q0; p1 = q1; p2 = q2; p3 = q3;
          w0 = v0; w1 = v1; w2 = v2; w3 = v3;
        }
        ma0 += bch(w0.x) * bch(p0.y); mc0 += bch(w0.y) * bch(p0.y);
        ma1 += bch(w1.x) * bch(p1.y); mc1 += bch(w1.y) * bch(p1.y);
        ma0 += bch(w2.x) * bch(p2.y); mc0 += bch(w2.y) * bch(p2.y);
        ma1 += bch(w3.x) * bch(p3.y); mc1 += bch(w3.y) * bch(p3.y);
      }
      float4 s4;
      s4.x = (float)ma0.x + (float)ma1.x; s4.y = (float)ma0.y + (float)ma1.y;
      s4.z = (float)mc0.x + (float)mc1.x; s4.w = (float)mc0.y + (float)mc1.y;
      ((float4*)(pm + slice * DH))[q] = s4;
    }
    __syncthreads();                                     // B0

    float base_i = 0.f;
    if (lower) {
      base_i = bh_i + zg;
      if (t > 0) {
        float ps = 0.f;
        #pragma unroll
        for (int sl = 0; sl < 8; ++sl) ps += pm[sl * DH + dim];
        base_i += ps;
      }
    }

    for (int inr = 0; inr <= S_INNER; ++inr) {
      // ---- phase A (owners): x = base + Ah; DPP sums; lane63 publishes
      float x = 0.f;
      if (lower) {
        float Ah = 0.f;
        if (inr > 0 && t > 0) {
          const uint4* cbp = (const uint4*)cbufh2;
          uint4 c0 = cbp[0], c1 = cbp[1], c2 = cbp[2];
          uint4 c3 = cbp[3], c4 = cbp[4], c5 = cbp[5];
          float A0 = 0.f, A1 = 0.f, A2 = 0.f, A3 = 0.f;
          A0 = fdot2u(hreg[0],  c0.x, A0); A1 = fdot2u(hreg[1],  c0.y, A1);
          A2 = fdot2u(hreg[2],  c0.z, A2); A3 = fdot2u(hreg[3],  c0.w, A3);
          A0 = fdot2u(hreg[4],  c1.x, A0); A1 = fdot2u(hreg[5],  c1.y, A1);
          A2 = fdot2u(hreg[6],  c1.z, A2); A3 = fdot2u(hreg[7],  c1.w, A3);
          A0 = fdot2u(hreg[8],  c2.x, A0); A1 = fdot2u(hreg[9],  c2.y, A1);
          A2 = fdot2u(hreg[10], c2.z, A2); A3 = fdot2u(hreg[11], c2.w, A3);
          A0 = fdot2u(hreg[12], c3.x, A0); A1 = fdot2u(hreg[13], c3.y, A1);
          A2 = fdot2u(hreg[14], c3.z, A2); A3 = fdot2u(hreg[15], c3.w, A3);
          A0 = fdot2u(hreg[16], c4.x, A0); A1 = fdot2u(hreg[17], c4.y, A1);
          A2 = fdot2u(hreg[18], c4.z, A2); A3 = fdot2u(hreg[19], c4.w, A3);
          A0 = fdot2u(hreg[20], c5.x, A0); A1 = fdot2u(hreg[21], c5.y, A1);
          A2 = fdot2u(hreg[22], c5.z, A2); A3 = fdot2u(hreg[23], c5.w, A3);
          Ah = (A0 + A1) + (A2 + A3);
        }
        x = base_i + Ah;
        float sa = wave64_sum63(x);
        float sb = wave64_sum63(x * x);
        if (lane == 63) red[wv] = make_float2(sa, sb);
      }
      __syncthreads();                                   // B1

      if (inr < S_INNER) {
        // ---- phase B (owners): LN -> h, publish packed pairs
        if (lower) {
          const float4* rr = (const float4*)red;
          float4 r0 = rr[0], r1 = rr[1], r2 = rr[2], r3 = rr[3];
          float s  = ((r0.x + r1.x) + (r2.x + r3.x)) + ((r0.z + r1.z) + (r2.z + r3.z));
          float s2 = ((r0.y + r1.y) + (r2.y + r3.y)) + ((r0.w + r1.w) + (r2.w + r3.w));
          const float inv = 1.f / (float)DH;
          float mu  = s * inv;
          float var = s2 * inv - mu * mu;
          float rstd = rsqrtf(var + 1e-5f);
          float h = fmaxf(fmaf((x - mu) * rstd, g_i, be_i), 0.f);
          float hn = dpp_mov<0xB1>(h);
          if (!(dim & 1)) h2cur[dim >> 1] = pkh((_Float16)h, (_Float16)hn);
        }
        __syncthreads();                                 // B2
        // ---- phase C (dot engines): c_s from prefetched hist regs + h2cur
        if (isdot) {
          const unsigned* hp = h2cur + 16 * dj;
          uint4 v0 = *(const uint4*)(hp + 0);
          uint4 v1 = *(const uint4*)(hp + 4);
          uint4 v2 = *(const uint4*)(hp + 8);
          uint4 v3 = *(const uint4*)(hp + 12);
          float a0 = 0.f, a1 = 0.f, a2 = 0.f, a3 = 0.f;
          a0 = fdot2u(hr0.x, v0.x, a0); a1 = fdot2u(hr0.y, v0.y, a1);
          a2 = fdot2u(hr0.z, v0.z, a2); a3 = fdot2u(hr0.w, v0.w, a3);
          a0 = fdot2u(hr1.x, v1.x, a0); a1 = fdot2u(hr1.y, v1.y, a1);
          a2 = fdot2u(hr1.z, v1.z, a2); a3 = fdot2u(hr1.w, v1.w, a3);
          a0 = fdot2u(hr2.x, v2.x, a0); a1 = fdot2u(hr2.y, v2.y, a1);
          a2 = fdot2u(hr2.z, v2.z, a2); a3 = fdot2u(hr2.w, v2.w, a3);
          a0 = fdot2u(hr3.x, v3.x, a0); a1 = fdot2u(hr3.y, v3.y, a1);
          a2 = fdot2u(hr3.z, v3.z, a2); a3 = fdot2u(hr3.w, v3.w, a3);
          float pd = row16_sum((a0 + a1) + (a2 + a3));
          float cc = (dst < t) ? pd * lampow[t - 1 - dst] : 0.f;
          if (dj == 0) {
            _Float16 ch = (_Float16)cc;
            ((unsigned short*)cbufh2)[dst] = __builtin_bit_cast(unsigned short, ch);
          }
        }
        __syncthreads();                                 // B3
      } else {
        // ---- final inner: owners materialize h, append history, ballot
        float h = 0.f;
        if (lower) {
          const float4* rr = (const float4*)red;
          float4 r0 = rr[0], r1 = rr[1], r2 = rr[2], r3 = rr[3];
          float s  = ((r0.x + r1.x) + (r2.x + r3.x)) + ((r0.z + r1.z) + (r2.z + r3.z));
          float s2 = ((r0.y + r1.y) + (r2.y + r3.y)) + ((r0.w + r1.w) + (r2.w + r3.w));
          const float inv = 1.f / (float)DH;
          float mu  = s * inv;
          float var = s2 * inv - mu * mu;
          float rstd = rsqrtf(var + 1e-5f);
          h = fmaxf(fmaf((x - mu) * rstd, g_i, be_i), 0.f);
          unsigned hb = (unsigned)__builtin_bit_cast(unsigned short, (_Float16)h);
          float hn = dpp_mov<0xB1>(h);
          if (!(dim & 1))
            histd[t * HDSTRIDE + (dim >> 1)] = pkh((_Float16)h, (_Float16)hn);
          switch (t) {
            HCASE(0)  HCASE(1)  HCASE(2)  HCASE(3)  HCASE(4)  HCASE(5)
            HCASE(6)  HCASE(7)  HCASE(8)  HCASE(9)  HCASE(10) HCASE(11)
            HCASE(12) HCASE(13) HCASE(14) HCASE(15) HCASE(16) HCASE(17)
            HCASE(18) HCASE(19) HCASE(20) HCASE(21) HCASE(22) HCASE(23)
          }
          if (t == T_STEPS - 1) hcur[dim] = h;
          unsigned long long mb = __ballot(h != 0.f);
          if (lane == 0) wcnt[wv] = __popcll(mb);
        }
        __syncthreads();                                 // B2
        int cnt = 0, wbase = 0;
        #pragma unroll
        for (int w = 0; w < 8; ++w) {
          int c = wcnt[w];
          if (w < wv) wbase += c;
          cnt += c;
        }
        if (lower && h != 0.f) {
          unsigned long long mb = __ballot(h != 0.f);
          int myoff = __popcll(mb & ((1ull << lane) - 1ull));
          _Float16 hh = (_Float16)h;
          uint2 ent; ent.x = (unsigned)(dim << 7); ent.y = pkh(hh, hh);
          AP[wbase + myoff] = ent;
        }
        cntp = (cnt + 31) & ~31;
        if (tid < cntp - cnt) { uint2 zz; zz.x = 0u; zz.y = 0u; AP[cnt + tid] = zz; }
        __syncthreads();                                 // B3
      }
    }
  }

  // ---- epilogue: pred = h @ W_head^T + b_head, then loss/acc
  for (int r = wv; r < DG; r += 16) {
    const float4* w4  = (const float4*)(W_head + (size_t)r * DH);
    const float4* hc4 = (const float4*)hcur;
    float pdot = 0.f;
    #pragma unroll
    for (int kk = 0; kk < 2; ++kk) {
      float4 a4 = w4[lane + 64 * kk];
      float4 c4 = hc4[lane + 64 * kk];
      pdot += a4.x * c4.x + a4.y * c4.y + a4.z * c4.z + a4.w * c4.w;
    }
    pdot = wave_reduce_sum(pdot);
    if (lane == 0) pred[r] = pdot + b_head[r];
  }
  __syncthreads();

  float sq = 0.f, pc = 0.f, pp = 0.f, cc = 0.f;
  if (tid < DG) {
    float pv = pred[tid];
    float cv = clean[(size_t)b * DG + tid];
    float d = pv - cv;
    sq = d * d; pc = pv * cv; pp = pv * pv; cc = cv * cv;
  }
  #pragma unroll
  for (int off = 32; off > 0; off >>= 1) {
    sq += __shfl_xor(sq, off, 64);
    pc += __shfl_xor(pc, off, 64);
    pp += __shfl_xor(pp, off, 64);
    cc += __shfl_xor(cc, off, 64);
  }
  if (lane == 0) {
    red4[wv * 4 + 0] = sq; red4[wv * 4 + 1] = pc;
    red4[wv * 4 + 2] = pp; red4[wv * 4 + 3] = cc;
  }
  __syncthreads();
  if (tid == 0) {
    float Sq = 0.f, Pc = 0.f, Pp = 0.f, Cc = 0.f;
    #pragma unroll
    for (int w = 0; w < 16; ++w) {
      Sq += red4[w * 4 + 0]; Pc += red4[w * 4 + 1];
      Pp += red4[w * 4 + 2]; Cc += red4[w * 4 + 3];
    }
    outbuf[b]         = Sq / (Cc + 1e-6f);
    outbuf[BATCH + b] = Pc / ((sqrtf(Pp) + 1e-6f) * (sqrtf(Cc) + 1e-6f));
  }
}

__global__ __launch_bounds__(64)
void finalize_k(const float* __restrict__ outbuf, float* __restrict__ out) {
  int tid = threadIdx.x;
  float l = (tid < BATCH) ? outbuf[tid] : 0.f;
  float a = (tid < BATCH) ? outbuf[BATCH + tid] : 0.f;
  #pragma unroll
  for (int off = 32; off > 0; off >>= 1) {
    l += __shfl_xor(l, off, 64);
    a += __shfl_xor(a, off, 64);
  }
  if (tid == 0) {
    out[0] = l * (1.f / (float)BATCH);
    out[1] = a * (1.f / (float)BATCH);
  }
}

extern "C" void kernel_launch(void* const* d_in, const int* in_sizes, int n_in,
                              void* d_out, int out_size, void* d_ws, size_t ws_size,
                              hipStream_t stream) {
  (void)in_sizes; (void)n_in; (void)out_size; (void)ws_size;
  const float* z      = (const float*)d_in[0];
  const float* clean  = (const float*)d_in[1];
  const float* W_h    = (const float*)d_in[2];
  const float* W_g    = (const float*)d_in[3];
  const float* b_h    = (const float*)d_in[4];
  const float* gamma  = (const float*)d_in[5];
  const float* beta   = (const float*)d_in[6];
  const float* W_head = (const float*)d_in[7];
  const float* b_head = (const float*)d_in[8];

  float* wsf     = (float*)d_ws;
  uint2* Whq     = (uint2*)wsf;                           // 65536 uint2
  float* WgT     = wsf + 131072;                          // 256*512
  float* ZG      = WgT + (size_t)DG * DH;                 // 2304*512
  float* outbuf  = ZG + (size_t)T_STEPS * BATCH * DH;     // 96

  hipLaunchKernelGGL(pack_whq, dim3(256), dim3(256), 0, stream, W_h, Whq);
  hipLaunchKernelGGL(transpose_k, dim3(DG / 32, DH / 32), dim3(256), 0, stream,
                     W_g, WgT, DH, DG);
  hipLaunchKernelGGL(zg_kernel, dim3((T_STEPS * BATCH) / 8), dim3(DH), 0, stream,
                     z, WgT, ZG);
  hipLaunchKernelGGL(rnn_main, dim3(BATCH), dim3(1024), 0, stream,
                     ZG, Whq, b_h, gamma, beta, W_head, b_head, clean, outbuf);
  hipLaunchKernelGGL(finalize_k, dim3(1), dim3(64), 0, stream,
                     outbuf, (float*)d_out);
}

// Round 7
// 320.312 us; speedup vs baseline: 1.6575x; 1.0831x over previous
//
#include <hip/hip_runtime.h>

#define T_STEPS 48
#define BATCH   48
#define DG      256
#define DH      512
#define S_INNER 3
#define HDSTRIDE 260   // histd row stride in u32: +4-bank skew per row, 16B-aligned

typedef _Float16 hf2 __attribute__((ext_vector_type(2)));

__device__ __forceinline__ hf2 bch(unsigned u) { return __builtin_bit_cast(hf2, u); }
__device__ __forceinline__ unsigned pkh(_Float16 a, _Float16 b) {
  hf2 v{a, b}; return __builtin_bit_cast(unsigned, v);
}
__device__ __forceinline__ float fdot2u(unsigned a, unsigned b, float c) {
#if __has_builtin(__builtin_amdgcn_fdot2)
  return __builtin_amdgcn_fdot2(bch(a), bch(b), c, false);
#else
  hf2 x = bch(a), y = bch(b);
  return fmaf((float)x.x, (float)y.x, fmaf((float)x.y, (float)y.y, c));
#endif
}
__device__ __forceinline__ float wave_reduce_sum(float v) {
  #pragma unroll
  for (int off = 32; off > 0; off >>= 1) v += __shfl_xor(v, off, 64);
  return v;
}
template <int CTRL>
__device__ __forceinline__ float dpp_add(float v) {
  int t = __builtin_amdgcn_update_dpp(0, __float_as_int(v), CTRL, 0xf, 0xf, true);
  return v + __int_as_float(t);
}
template <int CTRL>
__device__ __forceinline__ float dpp_mov(float v) {
  return __int_as_float(
      __builtin_amdgcn_update_dpp(0, __float_as_int(v), CTRL, 0xf, 0xf, true));
}
// 64-lane sum, result valid in lane 63; zero LDS traffic
__device__ __forceinline__ float wave64_sum63(float v) {
  v = dpp_add<0xB1>(v);    // xor1 (quad_perm)
  v = dpp_add<0x4E>(v);    // xor2 (quad_perm)
  v = dpp_add<0x141>(v);   // row_half_mirror
  v = dpp_add<0x140>(v);   // row_mirror -> 16-row sums in all lanes
  v = dpp_add<0x142>(v);   // row_bcast15
  v = dpp_add<0x143>(v);   // row_bcast31 -> total in lane 63
  return v;
}
// sum over each 16-lane row, result in all 16 lanes of the row
__device__ __forceinline__ float row16_sum(float v) {
  v = dpp_add<0xB1>(v);
  v = dpp_add<0x4E>(v);
  v = dpp_add<0x141>(v);
  v = dpp_add<0x140>(v);
  return v;
}

// ---------- weight packing: Whq[j*128 + q] = 4 dims {4q..4q+3} of column j, fp16
__global__ __launch_bounds__(256)
void pack_whq(const float* __restrict__ W, uint2* __restrict__ Wq) {
  int idx = blockIdx.x * 256 + threadIdx.x;   // 65536
  int j = idx & (DH - 1), q = idx >> 9;
  float w0 = W[(size_t)(4 * q + 0) * DH + j];
  float w1 = W[(size_t)(4 * q + 1) * DH + j];
  float w2 = W[(size_t)(4 * q + 2) * DH + j];
  float w3 = W[(size_t)(4 * q + 3) * DH + j];
  uint2 o;
  o.x = pkh((_Float16)w0, (_Float16)w1);
  o.y = pkh((_Float16)w2, (_Float16)w3);
  Wq[(size_t)j * 128 + q] = o;
}

__global__ __launch_bounds__(256)
void transpose_k(const float* __restrict__ in, float* __restrict__ out, int R, int C) {
  __shared__ float tile[32][33];
  int c0 = blockIdx.x * 32, r0 = blockIdx.y * 32;
  int tx = threadIdx.x & 31, ty = threadIdx.x >> 5;
  #pragma unroll
  for (int k = 0; k < 32; k += 8)
    tile[ty + k][tx] = in[(size_t)(r0 + ty + k) * C + (c0 + tx)];
  __syncthreads();
  #pragma unroll
  for (int k = 0; k < 32; k += 8)
    out[(size_t)(c0 + ty + k) * R + (r0 + tx)] = tile[tx][ty + k];
}

__global__ __launch_bounds__(DH, 2)
void zg_kernel(const float* __restrict__ z, const float* __restrict__ WgT,
               float* __restrict__ ZG) {
  const int row0 = blockIdx.x * 8;
  const int tid = threadIdx.x;
  __shared__ __align__(16) float zl[8][DG];
  for (int i = tid; i < 8 * (DG / 4); i += DH) {
    int r = i >> 6, c = i & 63;
    ((float4*)zl[r])[c] = ((const float4*)(z + (size_t)(row0 + r) * DG))[c];
  }
  __syncthreads();
  float acc[8] = {0.f, 0.f, 0.f, 0.f, 0.f, 0.f, 0.f, 0.f};
  for (int j = 0; j < DG; j += 4) {
    float w0 = WgT[(size_t)(j + 0) * DH + tid];
    float w1 = WgT[(size_t)(j + 1) * DH + tid];
    float w2 = WgT[(size_t)(j + 2) * DH + tid];
    float w3 = WgT[(size_t)(j + 3) * DH + tid];
    #pragma unroll
    for (int r = 0; r < 8; ++r) {
      float4 zz = ((const float4*)zl[r])[j >> 2];
      acc[r] = fmaf(w0, zz.x, acc[r]);
      acc[r] = fmaf(w1, zz.y, acc[r]);
      acc[r] = fmaf(w2, zz.z, acc[r]);
      acc[r] = fmaf(w3, zz.w, acc[r]);
    }
  }
  #pragma unroll
  for (int r = 0; r < 8; ++r)
    ZG[(size_t)(row0 + r) * DH + tid] = acc[r];
}

#define HCASE(s) case (2*(s)): hreg[(s)] = hb; break; \
                 case (2*(s)+1): hreg[(s)] |= (hb << 16); break;

__global__ __launch_bounds__(1024, 4)
void rnn_main(const float* __restrict__ ZG, const uint2* __restrict__ Whq,
              const float* __restrict__ bh, const float* __restrict__ gamma,
              const float* __restrict__ beta, const float* __restrict__ W_head,
              const float* __restrict__ b_head, const float* __restrict__ clean,
              float* __restrict__ outbuf) {
  const int b = blockIdx.x;
  const int tid  = threadIdx.x;         // 1024 threads = 16 waves
  const int lane = tid & 63;
  const int wv   = tid >> 6;            // 0..15
  const int dim  = tid;                 // owner dim (tid < 512)
  const bool lower = tid < DH;          // waves 0..7: owners
  const int q     = tid & 127;          // matvec quad index
  const int slice = tid >> 7;           // matvec split-K slice 0..7
  const bool isdot = tid < 768;         // waves 0..11: dot engines
  const int dst = tid >> 4;             // dot row s (0..47)
  const int dj  = tid & 15;             // dot chunk id (owns chunks 4*dj + 64k)

  __shared__ __align__(16) unsigned histd[T_STEPS * HDSTRIDE];  // fp16 dim-pair history
  __shared__ __align__(16) float    pm[8 * DH];                 // split-K partials
  __shared__ __align__(16) uint2    AP[DH + 32];                // active list {byteoff, h2}
  __shared__ __align__(16) unsigned h2cur[256];                 // current h, dim-pairs
  __shared__ __align__(16) unsigned cbufh2[24];                 // c coeffs (48 fp16)
  __shared__ __align__(16) float    hcur[DH];
  __shared__ __align__(16) float    pred[DG];
  __shared__ float2 red[8];
  __shared__ float  red4[64];
  __shared__ int    wcnt[8];
  __shared__ float  lampow[T_STEPS];

  float g_i = 0.f, be_i = 0.f, bh_i = 0.f;
  if (lower) { g_i = gamma[dim]; be_i = beta[dim]; bh_i = bh[dim]; }
  if (tid == 0) {
    float pw = 0.5f;                    // eta folded in
    for (int k = 0; k < T_STEPS; ++k) { lampow[k] = pw; pw *= 0.95f; }
  }
  unsigned hreg[24];                    // owner's fp16 history column, s-pairs
  #pragma unroll
  for (int k = 0; k < 24; ++k) hreg[k] = 0u;

  const char* Wb = (const char*)Whq;    // SGPR base for saddr-form gathers
  const unsigned q8 = (unsigned)(q << 3);
  __syncthreads();

  int cntp = 0;    // padded active count (multiple of 32), uniform

  for (int t = 0; t < T_STEPS; ++t) {
    float zg = lower ? ZG[((size_t)t * BATCH + b) * DH + dim] : 0.f;

    // per-step prefetch: dot thread's chunks {4*dj + 64k} of hist row dst
    // (16 lanes of a quarter-group read consecutive 16B chunks -> conflict-free)
    uint4 hr0, hr1, hr2, hr3;
    if (isdot) {
      const unsigned* rp = histd + dst * HDSTRIDE + 4 * dj;
      hr0 = *(const uint4*)(rp + 0);
      hr1 = *(const uint4*)(rp + 64);
      hr2 = *(const uint4*)(rp + 128);
      hr3 = *(const uint4*)(rp + 192);
    } else {
      hr0 = hr1 = hr2 = hr3 = make_uint4(0u, 0u, 0u, 0u);
    }

    // ---- matvec: pm[slice][4q..4q+3] += W_h h_prev over this slice's actives
    {
      hf2 ma0{}, ma1{}, mc0{}, mc1{};
      const int n = cntp >> 3;          // per-slice entries, multiple of 4
      if (t > 0 && n > 0) {
        int e = slice;
        uint2 p0 = AP[e], p1 = AP[e + 8], p2 = AP[e + 16], p3 = AP[e + 24];
        uint2 w0 = *(const uint2*)(Wb + (p0.x + q8));
        uint2 w1 = *(const uint2*)(Wb + (p1.x + q8));
        uint2 w2 = *(const uint2*)(Wb + (p2.x + q8));
        uint2 w3 = *(const uint2*)(Wb + (p3.x + q8));
        for (int m = 4; m < n; m += 4) {
          e += 32;
          uint2 q0 = AP[e], q1 = AP[e + 8], q2 = AP[e + 16], q3 = AP[e + 24];
          uint2 v0 = *(const uint2*)(Wb + (q0.x + q8));
          uint2 v1 = *(const uint2*)(Wb + (q1.x + q8));
          uint2 v2 = *(const uint2*)(Wb + (q2.x + q8));
          uint2 v3 = *(const uint2*)(Wb + (q3.x + q8));
          ma0 += bch(w0.x) * bch(p0.y); mc0 += bch(w0.y) * bch(p0.y);
          ma1 += bch(w1.x) * bch(p1.y); mc1 += bch(w1.y) * bch(p1.y);
          ma0 += bch(w2.x) * bch(p2.y); mc0 += bch(w2.y) * bch(p2.y);
          ma1 += bch(w3.x) * bch(p3.y); mc1 += bch(w3.y) * bch(p3.y);
          p0 = q0; p1 = q1; p2 = q2; p3 = q3;
          w0 = v0; w1 = v1; w2 = v2; w3 = v3;
        }
        ma0 += bch(w0.x) * bch(p0.y); mc0 += bch(w0.y) * bch(p0.y);
        ma1 += bch(w1.x) * bch(p1.y); mc1 += bch(w1.y) * bch(p1.y);
        ma0 += bch(w2.x) * bch(p2.y); mc0 += bch(w2.y) * bch(p2.y);
        ma1 += bch(w3.x) * bch(p3.y); mc1 += bch(w3.y) * bch(p3.y);
      }
      float4 s4;
      s4.x = (float)ma0.x + (float)ma1.x; s4.y = (float)ma0.y + (float)ma1.y;
      s4.z = (float)mc0.x + (float)mc1.x; s4.w = (float)mc0.y + (float)mc1.y;
      ((float4*)(pm + slice * DH))[q] = s4;
    }
    __syncthreads();                                     // B0

    float base_i = 0.f;
    if (lower) {
      base_i = bh_i + zg;
      if (t > 0) {
        float ps = 0.f;
        #pragma unroll
        for (int sl = 0; sl < 8; ++sl) ps += pm[sl * DH + dim];
        base_i += ps;
      }
    }

    for (int inr = 0; inr <= S_INNER; ++inr) {
      // ---- phase A (owners): x = base + Ah; DPP sums; lane63 publishes
      float x = 0.f;
      if (lower) {
        float Ah = 0.f;
        if (inr > 0 && t > 0) {
          const uint4* cbp = (const uint4*)cbufh2;
          uint4 c0 = cbp[0], c1 = cbp[1], c2 = cbp[2];
          uint4 c3 = cbp[3], c4 = cbp[4], c5 = cbp[5];
          float A0 = 0.f, A1 = 0.f, A2 = 0.f, A3 = 0.f;
          A0 = fdot2u(hreg[0],  c0.x, A0); A1 = fdot2u(hreg[1],  c0.y, A1);
          A2 = fdot2u(hreg[2],  c0.z, A2); A3 = fdot2u(hreg[3],  c0.w, A3);
          A0 = fdot2u(hreg[4],  c1.x, A0); A1 = fdot2u(hreg[5],  c1.y, A1);
          A2 = fdot2u(hreg[6],  c1.z, A2); A3 = fdot2u(hreg[7],  c1.w, A3);
          A0 = fdot2u(hreg[8],  c2.x, A0); A1 = fdot2u(hreg[9],  c2.y, A1);
          A2 = fdot2u(hreg[10], c2.z, A2); A3 = fdot2u(hreg[11], c2.w, A3);
          A0 = fdot2u(hreg[12], c3.x, A0); A1 = fdot2u(hreg[13], c3.y, A1);
          A2 = fdot2u(hreg[14], c3.z, A2); A3 = fdot2u(hreg[15], c3.w, A3);
          A0 = fdot2u(hreg[16], c4.x, A0); A1 = fdot2u(hreg[17], c4.y, A1);
          A2 = fdot2u(hreg[18], c4.z, A2); A3 = fdot2u(hreg[19], c4.w, A3);
          A0 = fdot2u(hreg[20], c5.x, A0); A1 = fdot2u(hreg[21], c5.y, A1);
          A2 = fdot2u(hreg[22], c5.z, A2); A3 = fdot2u(hreg[23], c5.w, A3);
          Ah = (A0 + A1) + (A2 + A3);
        }
        x = base_i + Ah;
        float sa = wave64_sum63(x);
        float sb = wave64_sum63(x * x);
        if (lane == 63) red[wv] = make_float2(sa, sb);
      }
      __syncthreads();                                   // B1

      if (inr < S_INNER) {
        // ---- phase B (owners): LN -> h, publish packed pairs
        if (lower) {
          const float4* rr = (const float4*)red;
          float4 r0 = rr[0], r1 = rr[1], r2 = rr[2], r3 = rr[3];
          float s  = ((r0.x + r1.x) + (r2.x + r3.x)) + ((r0.z + r1.z) + (r2.z + r3.z));
          float s2 = ((r0.y + r1.y) + (r2.y + r3.y)) + ((r0.w + r1.w) + (r2.w + r3.w));
          const float inv = 1.f / (float)DH;
          float mu  = s * inv;
          float var = s2 * inv - mu * mu;
          float rstd = rsqrtf(var + 1e-5f);
          float h = fmaxf(fmaf((x - mu) * rstd, g_i, be_i), 0.f);
          float hn = dpp_mov<0xB1>(h);
          if (!(dim & 1)) h2cur[dim >> 1] = pkh((_Float16)h, (_Float16)hn);
        }
        __syncthreads();                                 // B2
        // ---- phase C (dot engines): c_s from prefetched hist regs + h2cur
        if (isdot) {
          const unsigned* hp = h2cur + 4 * dj;
          uint4 v0 = *(const uint4*)(hp + 0);
          uint4 v1 = *(const uint4*)(hp + 64);
          uint4 v2 = *(const uint4*)(hp + 128);
          uint4 v3 = *(const uint4*)(hp + 192);
          float a0 = 0.f, a1 = 0.f, a2 = 0.f, a3 = 0.f;
          a0 = fdot2u(hr0.x, v0.x, a0); a1 = fdot2u(hr0.y, v0.y, a1);
          a2 = fdot2u(hr0.z, v0.z, a2); a3 = fdot2u(hr0.w, v0.w, a3);
          a0 = fdot2u(hr1.x, v1.x, a0); a1 = fdot2u(hr1.y, v1.y, a1);
          a2 = fdot2u(hr1.z, v1.z, a2); a3 = fdot2u(hr1.w, v1.w, a3);
          a0 = fdot2u(hr2.x, v2.x, a0); a1 = fdot2u(hr2.y, v2.y, a1);
          a2 = fdot2u(hr2.z, v2.z, a2); a3 = fdot2u(hr2.w, v2.w, a3);
          a0 = fdot2u(hr3.x, v3.x, a0); a1 = fdot2u(hr3.y, v3.y, a1);
          a2 = fdot2u(hr3.z, v3.z, a2); a3 = fdot2u(hr3.w, v3.w, a3);
          float pd = row16_sum((a0 + a1) + (a2 + a3));
          float cc = (dst < t) ? pd * lampow[t - 1 - dst] : 0.f;
          if (dj == 0) {
            _Float16 ch = (_Float16)cc;
            ((unsigned short*)cbufh2)[dst] = __builtin_bit_cast(unsigned short, ch);
          }
        }
        __syncthreads();                                 // B3
      } else {
        // ---- final inner: owners materialize h, append history, ballot
        float h = 0.f;
        if (lower) {
          const float4* rr = (const float4*)red;
          float4 r0 = rr[0], r1 = rr[1], r2 = rr[2], r3 = rr[3];
          float s  = ((r0.x + r1.x) + (r2.x + r3.x)) + ((r0.z + r1.z) + (r2.z + r3.z));
          float s2 = ((r0.y + r1.y) + (r2.y + r3.y)) + ((r0.w + r1.w) + (r2.w + r3.w));
          const float inv = 1.f / (float)DH;
          float mu  = s * inv;
          float var = s2 * inv - mu * mu;
          float rstd = rsqrtf(var + 1e-5f);
          h = fmaxf(fmaf((x - mu) * rstd, g_i, be_i), 0.f);
          unsigned hb = (unsigned)__builtin_bit_cast(unsigned short, (_Float16)h);
          float hn = dpp_mov<0xB1>(h);
          if (!(dim & 1))
            histd[t * HDSTRIDE + (dim >> 1)] = pkh((_Float16)h, (_Float16)hn);
          switch (t) {
            HCASE(0)  HCASE(1)  HCASE(2)  HCASE(3)  HCASE(4)  HCASE(5)
            HCASE(6)  HCASE(7)  HCASE(8)  HCASE(9)  HCASE(10) HCASE(11)
            HCASE(12) HCASE(13) HCASE(14) HCASE(15) HCASE(16) HCASE(17)
            HCASE(18) HCASE(19) HCASE(20) HCASE(21) HCASE(22) HCASE(23)
          }
          if (t == T_STEPS - 1) hcur[dim] = h;
          unsigned long long mb = __ballot(h != 0.f);
          if (lane == 0) wcnt[wv] = __popcll(mb);
        }
        __syncthreads();                                 // B2
        int cnt = 0, wbase = 0;
        #pragma unroll
        for (int w = 0; w < 8; ++w) {
          int c = wcnt[w];
          if (w < wv) wbase += c;
          cnt += c;
        }
        if (lower && h != 0.f) {
          unsigned long long mb = __ballot(h != 0.f);
          int myoff = __popcll(mb & ((1ull << lane) - 1ull));
          _Float16 hh = (_Float16)h;
          uint2 ent; ent.x = (unsigned)(dim << 10); ent.y = pkh(hh, hh);
          AP[wbase + myoff] = ent;
        }
        cntp = (cnt + 31) & ~31;
        if (tid < cntp - cnt) { uint2 zz; zz.x = 0u; zz.y = 0u; AP[cnt + tid] = zz; }
        __syncthreads();                                 // B3
      }
    }
  }

  // ---- epilogue: pred = h @ W_head^T + b_head, then loss/acc
  for (int r = wv; r < DG; r += 16) {
    const float4* w4  = (const float4*)(W_head + (size_t)r * DH);
    const float4* hc4 = (const float4*)hcur;
    float pdot = 0.f;
    #pragma unroll
    for (int kk = 0; kk < 2; ++kk) {
      float4 a4 = w4[lane + 64 * kk];
      float4 c4 = hc4[lane + 64 * kk];
      pdot += a4.x * c4.x + a4.y * c4.y + a4.z * c4.z + a4.w * c4.w;
    }
    pdot = wave_reduce_sum(pdot);
    if (lane == 0) pred[r] = pdot + b_head[r];
  }
  __syncthreads();

  float sq = 0.f, pc = 0.f, pp = 0.f, cc = 0.f;
  if (tid < DG) {
    float pv = pred[tid];
    float cv = clean[(size_t)b * DG + tid];
    float d = pv - cv;
    sq = d * d; pc = pv * cv; pp = pv * pv; cc = cv * cv;
  }
  #pragma unroll
  for (int off = 32; off > 0; off >>= 1) {
    sq += __shfl_xor(sq, off, 64);
    pc += __shfl_xor(pc, off, 64);
    pp += __shfl_xor(pp, off, 64);
    cc += __shfl_xor(cc, off, 64);
  }
  if (lane == 0) {
    red4[wv * 4 + 0] = sq; red4[wv * 4 + 1] = pc;
    red4[wv * 4 + 2] = pp; red4[wv * 4 + 3] = cc;
  }
  __syncthreads();
  if (tid == 0) {
    float Sq = 0.f, Pc = 0.f, Pp = 0.f, Cc = 0.f;
    #pragma unroll
    for (int w = 0; w < 16; ++w) {
      Sq += red4[w * 4 + 0]; Pc += red4[w * 4 + 1];
      Pp += red4[w * 4 + 2]; Cc += red4[w * 4 + 3];
    }
    outbuf[b]         = Sq / (Cc + 1e-6f);
    outbuf[BATCH + b] = Pc / ((sqrtf(Pp) + 1e-6f) * (sqrtf(Cc) + 1e-6f));
  }
}

__global__ __launch_bounds__(64)
void finalize_k(const float* __restrict__ outbuf, float* __restrict__ out) {
  int tid = threadIdx.x;
  float l = (tid < BATCH) ? outbuf[tid] : 0.f;
  float a = (tid < BATCH) ? outbuf[BATCH + tid] : 0.f;
  #pragma unroll
  for (int off = 32; off > 0; off >>= 1) {
    l += __shfl_xor(l, off, 64);
    a += __shfl_xor(a, off, 64);
  }
  if (tid == 0) {
    out[0] = l * (1.f / (float)BATCH);
    out[1] = a * (1.f / (float)BATCH);
  }
}

extern "C" void kernel_launch(void* const* d_in, const int* in_sizes, int n_in,
                              void* d_out, int out_size, void* d_ws, size_t ws_size,
                              hipStream_t stream) {
  (void)in_sizes; (void)n_in; (void)out_size; (void)ws_size;
  const float* z      = (const float*)d_in[0];
  const float* clean  = (const float*)d_in[1];
  const float* W_h    = (const float*)d_in[2];
  const float* W_g    = (const float*)d_in[3];
  const float* b_h    = (const float*)d_in[4];
  const float* gamma  = (const float*)d_in[5];
  const float* beta   = (const float*)d_in[6];
  const float* W_head = (const float*)d_in[7];
  const float* b_head = (const float*)d_in[8];

  float* wsf     = (float*)d_ws;
  uint2* Whq     = (uint2*)wsf;                           // 65536 uint2
  float* WgT     = wsf + 131072;                          // 256*512
  float* ZG      = WgT + (size_t)DG * DH;                 // 2304*512
  float* outbuf  = ZG + (size_t)T_STEPS * BATCH * DH;     // 96

  hipLaunchKernelGGL(pack_whq, dim3(256), dim3(256), 0, stream, W_h, Whq);
  hipLaunchKernelGGL(transpose_k, dim3(DG / 32, DH / 32), dim3(256), 0, stream,
                     W_g, WgT, DH, DG);
  hipLaunchKernelGGL(zg_kernel, dim3((T_STEPS * BATCH) / 8), dim3(DH), 0, stream,
                     z, WgT, ZG);
  hipLaunchKernelGGL(rnn_main, dim3(BATCH), dim3(1024), 0, stream,
                     ZG, Whq, b_h, gamma, beta, W_head, b_head, clean, outbuf);
  hipLaunchKernelGGL(finalize_k, dim3(1), dim3(64), 0, stream,
                     outbuf, (float*)d_out);
}

// Round 8
// 306.618 us; speedup vs baseline: 1.7315x; 1.0447x over previous
//
#include <hip/hip_runtime.h>

#define T_STEPS 48
#define BATCH   48
#define DG      256
#define DH      512
#define S_INNER 3
#define HDSTRIDE 260   // histd row stride in u32: +4-bank skew per row, 16B-aligned

typedef _Float16 hf2 __attribute__((ext_vector_type(2)));

__device__ __forceinline__ hf2 bch(unsigned u) { return __builtin_bit_cast(hf2, u); }
__device__ __forceinline__ unsigned pkh(_Float16 a, _Float16 b) {
  hf2 v{a, b}; return __builtin_bit_cast(unsigned, v);
}
__device__ __forceinline__ float fdot2u(unsigned a, unsigned b, float c) {
#if __has_builtin(__builtin_amdgcn_fdot2)
  return __builtin_amdgcn_fdot2(bch(a), bch(b), c, false);
#else
  hf2 x = bch(a), y = bch(b);
  return fmaf((float)x.x, (float)y.x, fmaf((float)x.y, (float)y.y, c));
#endif
}
__device__ __forceinline__ float wave_reduce_sum(float v) {
  #pragma unroll
  for (int off = 32; off > 0; off >>= 1) v += __shfl_xor(v, off, 64);
  return v;
}
template <int CTRL>
__device__ __forceinline__ float dpp_add(float v) {
  int t = __builtin_amdgcn_update_dpp(0, __float_as_int(v), CTRL, 0xf, 0xf, true);
  return v + __int_as_float(t);
}
template <int CTRL>
__device__ __forceinline__ float dpp_mov(float v) {
  return __int_as_float(
      __builtin_amdgcn_update_dpp(0, __float_as_int(v), CTRL, 0xf, 0xf, true));
}
// 64-lane sum, result valid in lane 63; zero LDS traffic
__device__ __forceinline__ float wave64_sum63(float v) {
  v = dpp_add<0xB1>(v);    // xor1 (quad_perm)
  v = dpp_add<0x4E>(v);    // xor2 (quad_perm)
  v = dpp_add<0x141>(v);   // row_half_mirror
  v = dpp_add<0x140>(v);   // row_mirror -> 16-row sums in all lanes
  v = dpp_add<0x142>(v);   // row_bcast15
  v = dpp_add<0x143>(v);   // row_bcast31 -> total in lane 63
  return v;
}
// sum over each 16-lane row, result in all 16 lanes of the row
__device__ __forceinline__ float row16_sum(float v) {
  v = dpp_add<0xB1>(v);
  v = dpp_add<0x4E>(v);
  v = dpp_add<0x141>(v);
  v = dpp_add<0x140>(v);
  return v;
}

// ---------- weight packing: Whq[j*128 + q] = 4 dims {4q..4q+3} of column j, fp16
__global__ __launch_bounds__(256)
void pack_whq(const float* __restrict__ W, uint2* __restrict__ Wq) {
  int idx = blockIdx.x * 256 + threadIdx.x;   // 65536
  int j = idx & (DH - 1), q = idx >> 9;
  float w0 = W[(size_t)(4 * q + 0) * DH + j];
  float w1 = W[(size_t)(4 * q + 1) * DH + j];
  float w2 = W[(size_t)(4 * q + 2) * DH + j];
  float w3 = W[(size_t)(4 * q + 3) * DH + j];
  uint2 o;
  o.x = pkh((_Float16)w0, (_Float16)w1);
  o.y = pkh((_Float16)w2, (_Float16)w3);
  Wq[(size_t)j * 128 + q] = o;
}

__global__ __launch_bounds__(256)
void transpose_k(const float* __restrict__ in, float* __restrict__ out, int R, int C) {
  __shared__ float tile[32][33];
  int c0 = blockIdx.x * 32, r0 = blockIdx.y * 32;
  int tx = threadIdx.x & 31, ty = threadIdx.x >> 5;
  #pragma unroll
  for (int k = 0; k < 32; k += 8)
    tile[ty + k][tx] = in[(size_t)(r0 + ty + k) * C + (c0 + tx)];
  __syncthreads();
  #pragma unroll
  for (int k = 0; k < 32; k += 8)
    out[(size_t)(c0 + ty + k) * R + (r0 + tx)] = tile[tx][ty + k];
}

__global__ __launch_bounds__(DH, 2)
void zg_kernel(const float* __restrict__ z, const float* __restrict__ WgT,
               float* __restrict__ ZG) {
  const int row0 = blockIdx.x * 8;
  const int tid = threadIdx.x;
  __shared__ __align__(16) float zl[8][DG];
  for (int i = tid; i < 8 * (DG / 4); i += DH) {
    int r = i >> 6, c = i & 63;
    ((float4*)zl[r])[c] = ((const float4*)(z + (size_t)(row0 + r) * DG))[c];
  }
  __syncthreads();
  float acc[8] = {0.f, 0.f, 0.f, 0.f, 0.f, 0.f, 0.f, 0.f};
  for (int j = 0; j < DG; j += 4) {
    float w0 = WgT[(size_t)(j + 0) * DH + tid];
    float w1 = WgT[(size_t)(j + 1) * DH + tid];
    float w2 = WgT[(size_t)(j + 2) * DH + tid];
    float w3 = WgT[(size_t)(j + 3) * DH + tid];
    #pragma unroll
    for (int r = 0; r < 8; ++r) {
      float4 zz = ((const float4*)zl[r])[j >> 2];
      acc[r] = fmaf(w0, zz.x, acc[r]);
      acc[r] = fmaf(w1, zz.y, acc[r]);
      acc[r] = fmaf(w2, zz.z, acc[r]);
      acc[r] = fmaf(w3, zz.w, acc[r]);
    }
  }
  #pragma unroll
  for (int r = 0; r < 8; ++r)
    ZG[(size_t)(row0 + r) * DH + tid] = acc[r];
}

#define HCASE(s) case (2*(s)): hreg[(s)] = hb; break; \
                 case (2*(s)+1): hreg[(s)] |= (hb << 16); break;

__global__ __launch_bounds__(1024, 4)
void rnn_main(const float* __restrict__ ZG, const uint2* __restrict__ Whq,
              const float* __restrict__ bh, const float* __restrict__ gamma,
              const float* __restrict__ beta, const float* __restrict__ W_head,
              const float* __restrict__ b_head, const float* __restrict__ clean,
              float* __restrict__ outbuf) {
  const int b = blockIdx.x;
  const int tid  = threadIdx.x;         // 1024 threads = 16 waves
  const int lane = tid & 63;
  const int wv   = tid >> 6;            // 0..15
  const int dim  = tid;                 // owner dim (tid < 512)
  const bool lower = tid < DH;          // waves 0..7: owners
  const int q     = tid & 127;          // matvec quad index
  const int slice = tid >> 7;           // matvec slice == region 0..7
  const bool isdot = tid < 768;         // waves 0..11: dot engines
  const int dst = tid >> 4;             // dot row s (0..47)
  const int dj  = tid & 15;             // dot chunk id (owns chunks 4*dj + 64k)

  __shared__ __align__(16) unsigned histd[T_STEPS * HDSTRIDE];  // fp16 dim-pair history
  __shared__ __align__(16) float    pm[8 * DH];                 // split-K partials
  __shared__ __align__(16) uint2    APr[8 * 64];                // per-wave-region actives
  __shared__ __align__(16) unsigned h2cur[256];                 // current h, dim-pairs
  __shared__ __align__(16) unsigned cbufh2[24];                 // c coeffs (48 fp16)
  __shared__ __align__(16) float    hcur[DH];
  __shared__ __align__(16) float    pred[DG];
  __shared__ float2 red[8];
  __shared__ float  red4[64];
  __shared__ int    wcntp[8];
  __shared__ float  lampow[T_STEPS];

  float g_i = 0.f, be_i = 0.f, bh_i = 0.f;
  if (lower) { g_i = gamma[dim]; be_i = beta[dim]; bh_i = bh[dim]; }
  if (tid == 0) {
    float pw = 0.5f;                    // eta folded in
    for (int k = 0; k < T_STEPS; ++k) { lampow[k] = pw; pw *= 0.95f; }
  }
  unsigned hreg[24];                    // owner's fp16 history column, s-pairs
  #pragma unroll
  for (int k = 0; k < 24; ++k) hreg[k] = 0u;

  const char* Wb = (const char*)Whq;    // SGPR base for saddr-form gathers
  const unsigned q8 = (unsigned)(q << 3);
  __syncthreads();

  for (int t = 0; t < T_STEPS; ++t) {
    float zg = lower ? ZG[((size_t)t * BATCH + b) * DH + dim] : 0.f;

    // per-step prefetch: dot thread's chunks {4*dj + 64k} of hist row dst
    uint4 hr0, hr1, hr2, hr3;
    if (isdot) {
      const unsigned* rp = histd + dst * HDSTRIDE + 4 * dj;
      hr0 = *(const uint4*)(rp + 0);
      hr1 = *(const uint4*)(rp + 64);
      hr2 = *(const uint4*)(rp + 128);
      hr3 = *(const uint4*)(rp + 192);
    } else {
      hr0 = hr1 = hr2 = hr3 = make_uint4(0u, 0u, 0u, 0u);
    }

    // ---- matvec: slice s handles region s's active columns for its 4 dims
    {
      hf2 ma0{}, ma1{}, mc0{}, mc1{};
      if (t > 0) {
        const int n = wcntp[slice];     // padded count, multiple of 4, uniform
        if (n > 0) {
          const uint4* ap4 = (const uint4*)(APr + slice * 64);
          uint4 E0 = ap4[0], E1 = ap4[1];
          uint2 w0 = *(const uint2*)(Wb + (E0.x + q8));
          uint2 w1 = *(const uint2*)(Wb + (E0.z + q8));
          uint2 w2 = *(const uint2*)(Wb + (E1.x + q8));
          uint2 w3 = *(const uint2*)(Wb + (E1.z + q8));
          for (int m = 4; m < n; m += 4) {
            uint4 F0 = ap4[m >> 1], F1 = ap4[(m >> 1) + 1];
            uint2 v0 = *(const uint2*)(Wb + (F0.x + q8));
            uint2 v1 = *(const uint2*)(Wb + (F0.z + q8));
            uint2 v2 = *(const uint2*)(Wb + (F1.x + q8));
            uint2 v3 = *(const uint2*)(Wb + (F1.z + q8));
            ma0 += bch(w0.x) * bch(E0.y); mc0 += bch(w0.y) * bch(E0.y);
            ma1 += bch(w1.x) * bch(E0.w); mc1 += bch(w1.y) * bch(E0.w);
            ma0 += bch(w2.x) * bch(E1.y); mc0 += bch(w2.y) * bch(E1.y);
            ma1 += bch(w3.x) * bch(E1.w); mc1 += bch(w3.y) * bch(E1.w);
            E0 = F0; E1 = F1;
            w0 = v0; w1 = v1; w2 = v2; w3 = v3;
          }
          ma0 += bch(w0.x) * bch(E0.y); mc0 += bch(w0.y) * bch(E0.y);
          ma1 += bch(w1.x) * bch(E0.w); mc1 += bch(w1.y) * bch(E0.w);
          ma0 += bch(w2.x) * bch(E1.y); mc0 += bch(w2.y) * bch(E1.y);
          ma1 += bch(w3.x) * bch(E1.w); mc1 += bch(w3.y) * bch(E1.w);
        }
      }
      float4 s4;
      s4.x = (float)ma0.x + (float)ma1.x; s4.y = (float)ma0.y + (float)ma1.y;
      s4.z = (float)mc0.x + (float)mc1.x; s4.w = (float)mc0.y + (float)mc1.y;
      ((float4*)(pm + slice * DH))[q] = s4;
    }
    __syncthreads();                                     // B0

    float base_i = 0.f;
    if (lower) {
      base_i = bh_i + zg;
      if (t > 0) {
        float ps = 0.f;
        #pragma unroll
        for (int sl = 0; sl < 8; ++sl) ps += pm[sl * DH + dim];
        base_i += ps;
      }
    }

    for (int inr = 0; inr <= S_INNER; ++inr) {
      // ---- phase A (owners): x = base + Ah; DPP sums; lane63 publishes
      float x = 0.f;
      if (lower) {
        float Ah = 0.f;
        if (inr > 0 && t > 0) {
          const uint4* cbp = (const uint4*)cbufh2;
          uint4 c0 = cbp[0], c1 = cbp[1], c2 = cbp[2];
          uint4 c3 = cbp[3], c4 = cbp[4], c5 = cbp[5];
          float A0 = 0.f, A1 = 0.f, A2 = 0.f, A3 = 0.f;
          A0 = fdot2u(hreg[0],  c0.x, A0); A1 = fdot2u(hreg[1],  c0.y, A1);
          A2 = fdot2u(hreg[2],  c0.z, A2); A3 = fdot2u(hreg[3],  c0.w, A3);
          A0 = fdot2u(hreg[4],  c1.x, A0); A1 = fdot2u(hreg[5],  c1.y, A1);
          A2 = fdot2u(hreg[6],  c1.z, A2); A3 = fdot2u(hreg[7],  c1.w, A3);
          A0 = fdot2u(hreg[8],  c2.x, A0); A1 = fdot2u(hreg[9],  c2.y, A1);
          A2 = fdot2u(hreg[10], c2.z, A2); A3 = fdot2u(hreg[11], c2.w, A3);
          A0 = fdot2u(hreg[12], c3.x, A0); A1 = fdot2u(hreg[13], c3.y, A1);
          A2 = fdot2u(hreg[14], c3.z, A2); A3 = fdot2u(hreg[15], c3.w, A3);
          A0 = fdot2u(hreg[16], c4.x, A0); A1 = fdot2u(hreg[17], c4.y, A1);
          A2 = fdot2u(hreg[18], c4.z, A2); A3 = fdot2u(hreg[19], c4.w, A3);
          A0 = fdot2u(hreg[20], c5.x, A0); A1 = fdot2u(hreg[21], c5.y, A1);
          A2 = fdot2u(hreg[22], c5.z, A2); A3 = fdot2u(hreg[23], c5.w, A3);
          Ah = (A0 + A1) + (A2 + A3);
        }
        x = base_i + Ah;
        float sa = wave64_sum63(x);
        float sb = wave64_sum63(x * x);
        if (lane == 63) red[wv] = make_float2(sa, sb);
      }
      __syncthreads();                                   // B1

      if (inr < S_INNER) {
        // ---- phase B (owners): LN -> h, publish packed pairs
        if (lower) {
          const float4* rr = (const float4*)red;
          float4 r0 = rr[0], r1 = rr[1], r2 = rr[2], r3 = rr[3];
          float s  = ((r0.x + r1.x) + (r2.x + r3.x)) + ((r0.z + r1.z) + (r2.z + r3.z));
          float s2 = ((r0.y + r1.y) + (r2.y + r3.y)) + ((r0.w + r1.w) + (r2.w + r3.w));
          const float inv = 1.f / (float)DH;
          float mu  = s * inv;
          float var = s2 * inv - mu * mu;
          float rstd = rsqrtf(var + 1e-5f);
          float h = fmaxf(fmaf((x - mu) * rstd, g_i, be_i), 0.f);
          float hn = dpp_mov<0xB1>(h);
          if (!(dim & 1)) h2cur[dim >> 1] = pkh((_Float16)h, (_Float16)hn);
        }
        __syncthreads();                                 // B2
        // ---- phase C (dot engines): c_s from prefetched hist regs + h2cur
        if (isdot) {
          const unsigned* hp = h2cur + 4 * dj;
          uint4 v0 = *(const uint4*)(hp + 0);
          uint4 v1 = *(const uint4*)(hp + 64);
          uint4 v2 = *(const uint4*)(hp + 128);
          uint4 v3 = *(const uint4*)(hp + 192);
          float a0 = 0.f, a1 = 0.f, a2 = 0.f, a3 = 0.f;
          a0 = fdot2u(hr0.x, v0.x, a0); a1 = fdot2u(hr0.y, v0.y, a1);
          a2 = fdot2u(hr0.z, v0.z, a2); a3 = fdot2u(hr0.w, v0.w, a3);
          a0 = fdot2u(hr1.x, v1.x, a0); a1 = fdot2u(hr1.y, v1.y, a1);
          a2 = fdot2u(hr1.z, v1.z, a2); a3 = fdot2u(hr1.w, v1.w, a3);
          a0 = fdot2u(hr2.x, v2.x, a0); a1 = fdot2u(hr2.y, v2.y, a1);
          a2 = fdot2u(hr2.z, v2.z, a2); a3 = fdot2u(hr2.w, v2.w, a3);
          a0 = fdot2u(hr3.x, v3.x, a0); a1 = fdot2u(hr3.y, v3.y, a1);
          a2 = fdot2u(hr3.z, v3.z, a2); a3 = fdot2u(hr3.w, v3.w, a3);
          float pd = row16_sum((a0 + a1) + (a2 + a3));
          float cc = (dst < t) ? pd * lampow[t - 1 - dst] : 0.f;
          if (dj == 0) {
            _Float16 ch = (_Float16)cc;
            ((unsigned short*)cbufh2)[dst] = __builtin_bit_cast(unsigned short, ch);
          }
        }
        __syncthreads();                                 // B3
      } else {
        // ---- final inner: owners materialize h, append history,
        //      build per-wave-region active list (no cross-wave prefix)
        if (lower) {
          const float4* rr = (const float4*)red;
          float4 r0 = rr[0], r1 = rr[1], r2 = rr[2], r3 = rr[3];
          float s  = ((r0.x + r1.x) + (r2.x + r3.x)) + ((r0.z + r1.z) + (r2.z + r3.z));
          float s2 = ((r0.y + r1.y) + (r2.y + r3.y)) + ((r0.w + r1.w) + (r2.w + r3.w));
          const float inv = 1.f / (float)DH;
          float mu  = s * inv;
          float var = s2 * inv - mu * mu;
          float rstd = rsqrtf(var + 1e-5f);
          float h = fmaxf(fmaf((x - mu) * rstd, g_i, be_i), 0.f);
          unsigned hb = (unsigned)__builtin_bit_cast(unsigned short, (_Float16)h);
          float hn = dpp_mov<0xB1>(h);
          if (!(dim & 1))
            histd[t * HDSTRIDE + (dim >> 1)] = pkh((_Float16)h, (_Float16)hn);
          switch (t) {
            HCASE(0)  HCASE(1)  HCASE(2)  HCASE(3)  HCASE(4)  HCASE(5)
            HCASE(6)  HCASE(7)  HCASE(8)  HCASE(9)  HCASE(10) HCASE(11)
            HCASE(12) HCASE(13) HCASE(14) HCASE(15) HCASE(16) HCASE(17)
            HCASE(18) HCASE(19) HCASE(20) HCASE(21) HCASE(22) HCASE(23)
          }
          if (t == T_STEPS - 1) hcur[dim] = h;
          unsigned long long mb = __ballot(h != 0.f);
          int myoff = __popcll(mb & ((1ull << lane) - 1ull));
          int wc  = __popcll(mb);
          int wcp = (wc + 3) & ~3;
          if (h != 0.f) {
            _Float16 hh = (_Float16)h;
            uint2 ent; ent.x = (unsigned)(dim << 10); ent.y = pkh(hh, hh);
            APr[wv * 64 + myoff] = ent;
          } else {
            int inact = lane - myoff;
            if (inact < wcp - wc) {
              uint2 zz; zz.x = 0u; zz.y = 0u;
              APr[wv * 64 + wc + inact] = zz;
            }
          }
          if (lane == 0) wcntp[wv] = wcp;
        }
        __syncthreads();                                 // B3f
      }
    }
  }

  // ---- epilogue: pred = h @ W_head^T + b_head, then loss/acc
  for (int r = wv; r < DG; r += 16) {
    const float4* w4  = (const float4*)(W_head + (size_t)r * DH);
    const float4* hc4 = (const float4*)hcur;
    float pdot = 0.f;
    #pragma unroll
    for (int kk = 0; kk < 2; ++kk) {
      float4 a4 = w4[lane + 64 * kk];
      float4 c4 = hc4[lane + 64 * kk];
      pdot += a4.x * c4.x + a4.y * c4.y + a4.z * c4.z + a4.w * c4.w;
    }
    pdot = wave_reduce_sum(pdot);
    if (lane == 0) pred[r] = pdot + b_head[r];
  }
  __syncthreads();

  float sq = 0.f, pc = 0.f, pp = 0.f, cc = 0.f;
  if (tid < DG) {
    float pv = pred[tid];
    float cv = clean[(size_t)b * DG + tid];
    float d = pv - cv;
    sq = d * d; pc = pv * cv; pp = pv * pv; cc = cv * cv;
  }
  #pragma unroll
  for (int off = 32; off > 0; off >>= 1) {
    sq += __shfl_xor(sq, off, 64);
    pc += __shfl_xor(pc, off, 64);
    pp += __shfl_xor(pp, off, 64);
    cc += __shfl_xor(cc, off, 64);
  }
  if (lane == 0) {
    red4[wv * 4 + 0] = sq; red4[wv * 4 + 1] = pc;
    red4[wv * 4 + 2] = pp; red4[wv * 4 + 3] = cc;
  }
  __syncthreads();
  if (tid == 0) {
    float Sq = 0.f, Pc = 0.f, Pp = 0.f, Cc = 0.f;
    #pragma unroll
    for (int w = 0; w < 16; ++w) {
      Sq += red4[w * 4 + 0]; Pc += red4[w * 4 + 1];
      Pp += red4[w * 4 + 2]; Cc += red4[w * 4 + 3];
    }
    outbuf[b]         = Sq / (Cc + 1e-6f);
    outbuf[BATCH + b] = Pc / ((sqrtf(Pp) + 1e-6f) * (sqrtf(Cc) + 1e-6f));
  }
}

__global__ __launch_bounds__(64)
void finalize_k(const float* __restrict__ outbuf, float* __restrict__ out) {
  int tid = threadIdx.x;
  float l = (tid < BATCH) ? outbuf[tid] : 0.f;
  float a = (tid < BATCH) ? outbuf[BATCH + tid] : 0.f;
  #pragma unroll
  for (int off = 32; off > 0; off >>= 1) {
    l += __shfl_xor(l, off, 64);
    a += __shfl_xor(a, off, 64);
  }
  if (tid == 0) {
    out[0] = l * (1.f / (float)BATCH);
    out[1] = a * (1.f / (float)BATCH);
  }
}

extern "C" void kernel_launch(void* const* d_in, const int* in_sizes, int n_in,
                              void* d_out, int out_size, void* d_ws, size_t ws_size,
                              hipStream_t stream) {
  (void)in_sizes; (void)n_in; (void)out_size; (void)ws_size;
  const float* z      = (const float*)d_in[0];
  const float* clean  = (const float*)d_in[1];
  const float* W_h    = (const float*)d_in[2];
  const float* W_g    = (const float*)d_in[3];
  const float* b_h    = (const float*)d_in[4];
  const float* gamma  = (const float*)d_in[5];
  const float* beta   = (const float*)d_in[6];
  const float* W_head = (const float*)d_in[7];
  const float* b_head = (const float*)d_in[8];

  float* wsf     = (float*)d_ws;
  uint2* Whq     = (uint2*)wsf;                           // 65536 uint2
  float* WgT     = wsf + 131072;                          // 256*512
  float* ZG      = WgT + (size_t)DG * DH;                 // 2304*512
  float* outbuf  = ZG + (size_t)T_STEPS * BATCH * DH;     // 96

  hipLaunchKernelGGL(pack_whq, dim3(256), dim3(256), 0, stream, W_h, Whq);
  hipLaunchKernelGGL(transpose_k, dim3(DG / 32, DH / 32), dim3(256), 0, stream,
                     W_g, WgT, DH, DG);
  hipLaunchKernelGGL(zg_kernel, dim3((T_STEPS * BATCH) / 8), dim3(DH), 0, stream,
                     z, WgT, ZG);
  hipLaunchKernelGGL(rnn_main, dim3(BATCH), dim3(1024), 0, stream,
                     ZG, Whq, b_h, gamma, beta, W_head, b_head, clean, outbuf);
  hipLaunchKernelGGL(finalize_k, dim3(1), dim3(64), 0, stream,
                     outbuf, (float*)d_out);
}

// Round 9
// 286.570 us; speedup vs baseline: 1.8526x; 1.0700x over previous
//
#include <hip/hip_runtime.h>

#define T_STEPS 48
#define BATCH   48
#define DG      256
#define DH      512
#define S_INNER 3
#define HDSTRIDE 260   // histd row stride in u32: +4-bank skew per row, 16B-aligned

typedef _Float16 hf2 __attribute__((ext_vector_type(2)));

__device__ __forceinline__ hf2 bch(unsigned u) { return __builtin_bit_cast(hf2, u); }
__device__ __forceinline__ unsigned pkh(_Float16 a, _Float16 b) {
  hf2 v{a, b}; return __builtin_bit_cast(unsigned, v);
}
__device__ __forceinline__ float fdot2u(unsigned a, unsigned b, float c) {
#if __has_builtin(__builtin_amdgcn_fdot2)
  return __builtin_amdgcn_fdot2(bch(a), bch(b), c, false);
#else
  hf2 x = bch(a), y = bch(b);
  return fmaf((float)x.x, (float)y.x, fmaf((float)x.y, (float)y.y, c));
#endif
}
__device__ __forceinline__ float wave_reduce_sum(float v) {
  #pragma unroll
  for (int off = 32; off > 0; off >>= 1) v += __shfl_xor(v, off, 64);
  return v;
}
template <int CTRL>
__device__ __forceinline__ float dpp_add(float v) {
  int t = __builtin_amdgcn_update_dpp(0, __float_as_int(v), CTRL, 0xf, 0xf, true);
  return v + __int_as_float(t);
}
template <int CTRL>
__device__ __forceinline__ float dpp_mov(float v) {
  return __int_as_float(
      __builtin_amdgcn_update_dpp(0, __float_as_int(v), CTRL, 0xf, 0xf, true));
}
// 64-lane sum, result valid in lane 63; zero LDS traffic
__device__ __forceinline__ float wave64_sum63(float v) {
  v = dpp_add<0xB1>(v);    // xor1 (quad_perm)
  v = dpp_add<0x4E>(v);    // xor2 (quad_perm)
  v = dpp_add<0x141>(v);   // row_half_mirror
  v = dpp_add<0x140>(v);   // row_mirror
  v = dpp_add<0x142>(v);   // row_bcast15
  v = dpp_add<0x143>(v);   // row_bcast31 -> total in lane 63
  return v;
}
// sum over each 16-lane row, result in all 16 lanes of the row
__device__ __forceinline__ float row16_sum(float v) {
  v = dpp_add<0xB1>(v);
  v = dpp_add<0x4E>(v);
  v = dpp_add<0x141>(v);
  v = dpp_add<0x140>(v);
  return v;
}

// ---------- weight packing: Whq[j*128 + q] = 4 dims {4q..4q+3} of column j, fp16
__global__ __launch_bounds__(256)
void pack_whq(const float* __restrict__ W, uint2* __restrict__ Wq) {
  int idx = blockIdx.x * 256 + threadIdx.x;   // 65536
  int j = idx & (DH - 1), q = idx >> 9;
  float w0 = W[(size_t)(4 * q + 0) * DH + j];
  float w1 = W[(size_t)(4 * q + 1) * DH + j];
  float w2 = W[(size_t)(4 * q + 2) * DH + j];
  float w3 = W[(size_t)(4 * q + 3) * DH + j];
  uint2 o;
  o.x = pkh((_Float16)w0, (_Float16)w1);
  o.y = pkh((_Float16)w2, (_Float16)w3);
  Wq[(size_t)j * 128 + q] = o;
}

__global__ __launch_bounds__(256)
void transpose_k(const float* __restrict__ in, float* __restrict__ out, int R, int C) {
  __shared__ float tile[32][33];
  int c0 = blockIdx.x * 32, r0 = blockIdx.y * 32;
  int tx = threadIdx.x & 31, ty = threadIdx.x >> 5;
  #pragma unroll
  for (int k = 0; k < 32; k += 8)
    tile[ty + k][tx] = in[(size_t)(r0 + ty + k) * C + (c0 + tx)];
  __syncthreads();
  #pragma unroll
  for (int k = 0; k < 32; k += 8)
    out[(size_t)(c0 + ty + k) * R + (r0 + tx)] = tile[tx][ty + k];
}

__global__ __launch_bounds__(DH, 2)
void zg_kernel(const float* __restrict__ z, const float* __restrict__ WgT,
               float* __restrict__ ZG) {
  const int row0 = blockIdx.x * 8;
  const int tid = threadIdx.x;
  __shared__ __align__(16) float zl[8][DG];
  for (int i = tid; i < 8 * (DG / 4); i += DH) {
    int r = i >> 6, c = i & 63;
    ((float4*)zl[r])[c] = ((const float4*)(z + (size_t)(row0 + r) * DG))[c];
  }
  __syncthreads();
  float acc[8] = {0.f, 0.f, 0.f, 0.f, 0.f, 0.f, 0.f, 0.f};
  for (int j = 0; j < DG; j += 4) {
    float w0 = WgT[(size_t)(j + 0) * DH + tid];
    float w1 = WgT[(size_t)(j + 1) * DH + tid];
    float w2 = WgT[(size_t)(j + 2) * DH + tid];
    float w3 = WgT[(size_t)(j + 3) * DH + tid];
    #pragma unroll
    for (int r = 0; r < 8; ++r) {
      float4 zz = ((const float4*)zl[r])[j >> 2];
      acc[r] = fmaf(w0, zz.x, acc[r]);
      acc[r] = fmaf(w1, zz.y, acc[r]);
      acc[r] = fmaf(w2, zz.z, acc[r]);
      acc[r] = fmaf(w3, zz.w, acc[r]);
    }
  }
  #pragma unroll
  for (int r = 0; r < 8; ++r)
    ZG[(size_t)(row0 + r) * DH + tid] = acc[r];
}

#define HCASE(s) case (2*(s)): hreg[(s)] = hb; break; \
                 case (2*(s)+1): hreg[(s)] |= (hb << 16); break;

#define MVACC(E, wA, wB) do {                                        \
    hf2 h0 = bch((E).y), h1 = bch((E).w);                            \
    a0 += bch((wA).x) * h0; a1 += bch((wA).y) * h0;                  \
    a2 += bch((wA).z) * h0; a3 += bch((wA).w) * h0;                  \
    b0 += bch((wB).x) * h1; b1 += bch((wB).y) * h1;                  \
    b2 += bch((wB).z) * h1; b3 += bch((wB).w) * h1;                  \
  } while (0)

__global__ __launch_bounds__(512, 2)
void rnn_main(const float* __restrict__ ZG, const uint2* __restrict__ Whq,
              const float* __restrict__ bh, const float* __restrict__ gamma,
              const float* __restrict__ beta, const float* __restrict__ W_head,
              const float* __restrict__ b_head, const float* __restrict__ clean,
              float* __restrict__ outbuf) {
  const int b = blockIdx.x;
  const int tid  = threadIdx.x;         // 512 threads = 8 waves
  const int lane = tid & 63;
  const int wv   = tid >> 6;            // wave = matvec slice = active region
  const int dim  = tid;                 // owner dim (all threads own a dim)
  const int g    = tid >> 4;            // dot group 0..31 (row g; +row g+32 if g<16)
  const int dj   = tid & 15;            // chunk id within row
  const bool g16 = tid < 256;           // wave-uniform: groups 0..15 take 2 rows

  __shared__ __align__(16) unsigned histd[T_STEPS * HDSTRIDE];  // fp16 dim-pair history
  __shared__ __align__(16) float    pm[8 * DH];                 // per-slice partials
  __shared__ __align__(16) uint2    APr[8 * 64];                // per-wave-region actives
  __shared__ __align__(16) unsigned h2cur[256];                 // current h, dim-pairs
  __shared__ __align__(16) unsigned cbufh2[24];                 // c coeffs (48 fp16)
  __shared__ __align__(16) float    hcur[DH];
  __shared__ __align__(16) float    pred[DG];
  __shared__ __align__(16) float2   red[8];
  __shared__ float  red4[32];
  __shared__ int    wcntp[8];
  __shared__ float  lampow[T_STEPS];

  const float g_i  = gamma[dim];
  const float be_i = beta[dim];
  const float bh_i = bh[dim];
  if (tid == 0) {
    float pw = 0.5f;                    // eta folded in
    for (int k = 0; k < T_STEPS; ++k) { lampow[k] = pw; pw *= 0.95f; }
  }
  unsigned hreg[24];                    // owner's fp16 history column, s-pairs
  #pragma unroll
  for (int k = 0; k < 24; ++k) hreg[k] = 0u;

  const char* Wb = (const char*)Whq;    // SGPR base for saddr-form gathers
  const unsigned l16 = (unsigned)(lane << 4);
  __syncthreads();

  for (int t = 0; t < T_STEPS; ++t) {
    float zg = ZG[((size_t)t * BATCH + b) * DH + dim];

    // per-step prefetch: this thread's chunks {4*dj + 64k} of dot rows g (+g+32)
    uint4 hA0, hA1, hA2, hA3, hB0, hB1, hB2, hB3;
    {
      const unsigned* rpA = histd + g * HDSTRIDE + 4 * dj;
      hA0 = *(const uint4*)(rpA + 0);
      hA1 = *(const uint4*)(rpA + 64);
      hA2 = *(const uint4*)(rpA + 128);
      hA3 = *(const uint4*)(rpA + 192);
      if (g16) {
        const unsigned* rpB = histd + (32 + g) * HDSTRIDE + 4 * dj;
        hB0 = *(const uint4*)(rpB + 0);
        hB1 = *(const uint4*)(rpB + 64);
        hB2 = *(const uint4*)(rpB + 128);
        hB3 = *(const uint4*)(rpB + 192);
      } else {
        hB0 = hB1 = hB2 = hB3 = make_uint4(0u, 0u, 0u, 0u);
      }
    }

    // ---- matvec: wave wv handles region wv; lane covers dims 8*lane..8*lane+7
    {
      hf2 a0{}, a1{}, a2{}, a3{}, b0{}, b1{}, b2{}, b3{};
      if (t > 0) {
        const int n = wcntp[wv];        // even, uniform in wave
        if (n > 0) {
          const uint4* ap4 = (const uint4*)(APr + wv * 64);  // entry pairs
          const int G = n >> 1;
          uint4 E0 = ap4[0];
          uint4 wA = *(const uint4*)(Wb + (E0.x + l16));
          uint4 wB = *(const uint4*)(Wb + (E0.z + l16));
          uint4 E1 = E0; uint4 wC = wA, wD = wB;
          if (G > 1) {
            E1 = ap4[1];
            wC = *(const uint4*)(Wb + (E1.x + l16));
            wD = *(const uint4*)(Wb + (E1.z + l16));
          }
          for (int grp = 2; grp < G; ++grp) {
            uint4 E2 = ap4[grp];
            uint4 wE = *(const uint4*)(Wb + (E2.x + l16));
            uint4 wF = *(const uint4*)(Wb + (E2.z + l16));
            MVACC(E0, wA, wB);
            E0 = E1; wA = wC; wB = wD;
            E1 = E2; wC = wE; wD = wF;
          }
          MVACC(E0, wA, wB);
          if (G > 1) MVACC(E1, wC, wD);
        }
      }
      float4 s0, s1;
      s0.x = (float)a0.x + (float)b0.x; s0.y = (float)a0.y + (float)b0.y;
      s0.z = (float)a1.x + (float)b1.x; s0.w = (float)a1.y + (float)b1.y;
      s1.x = (float)a2.x + (float)b2.x; s1.y = (float)a2.y + (float)b2.y;
      s1.z = (float)a3.x + (float)b3.x; s1.w = (float)a3.y + (float)b3.y;
      float4* pmw = (float4*)(pm + wv * DH);
      pmw[2 * lane + 0] = s0;
      pmw[2 * lane + 1] = s1;
    }
    __syncthreads();                                     // B0

    float base_i = bh_i + zg;
    if (t > 0) {
      float ps = 0.f;
      #pragma unroll
      for (int sl = 0; sl < 8; ++sl) ps += pm[sl * DH + dim];
      base_i += ps;
    }

    for (int inr = 0; inr <= S_INNER; ++inr) {
      // ---- phase A (all threads): x = base + Ah; DPP sums; lane63 publishes
      float x;
      {
        float Ah = 0.f;
        if (inr > 0 && t > 0) {
          const uint4* cbp = (const uint4*)cbufh2;
          uint4 c0 = cbp[0], c1 = cbp[1], c2 = cbp[2];
          uint4 c3 = cbp[3], c4 = cbp[4], c5 = cbp[5];
          float A0 = 0.f, A1 = 0.f, A2 = 0.f, A3 = 0.f;
          A0 = fdot2u(hreg[0],  c0.x, A0); A1 = fdot2u(hreg[1],  c0.y, A1);
          A2 = fdot2u(hreg[2],  c0.z, A2); A3 = fdot2u(hreg[3],  c0.w, A3);
          A0 = fdot2u(hreg[4],  c1.x, A0); A1 = fdot2u(hreg[5],  c1.y, A1);
          A2 = fdot2u(hreg[6],  c1.z, A2); A3 = fdot2u(hreg[7],  c1.w, A3);
          A0 = fdot2u(hreg[8],  c2.x, A0); A1 = fdot2u(hreg[9],  c2.y, A1);
          A2 = fdot2u(hreg[10], c2.z, A2); A3 = fdot2u(hreg[11], c2.w, A3);
          A0 = fdot2u(hreg[12], c3.x, A0); A1 = fdot2u(hreg[13], c3.y, A1);
          A2 = fdot2u(hreg[14], c3.z, A2); A3 = fdot2u(hreg[15], c3.w, A3);
          A0 = fdot2u(hreg[16], c4.x, A0); A1 = fdot2u(hreg[17], c4.y, A1);
          A2 = fdot2u(hreg[18], c4.z, A2); A3 = fdot2u(hreg[19], c4.w, A3);
          A0 = fdot2u(hreg[20], c5.x, A0); A1 = fdot2u(hreg[21], c5.y, A1);
          A2 = fdot2u(hreg[22], c5.z, A2); A3 = fdot2u(hreg[23], c5.w, A3);
          Ah = (A0 + A1) + (A2 + A3);
        }
        x = base_i + Ah;
        float sa = wave64_sum63(x);
        float sb = wave64_sum63(x * x);
        if (lane == 63) red[wv] = make_float2(sa, sb);
      }
      __syncthreads();                                   // B1
      float mu, rstd;
      {
        const float4* rr = (const float4*)red;
        float4 r0 = rr[0], r1 = rr[1], r2 = rr[2], r3 = rr[3];
        float s  = ((r0.x + r1.x) + (r2.x + r3.x)) + ((r0.z + r1.z) + (r2.z + r3.z));
        float s2 = ((r0.y + r1.y) + (r2.y + r3.y)) + ((r0.w + r1.w) + (r2.w + r3.w));
        const float inv = 1.f / (float)DH;
        mu = s * inv;
        float var = s2 * inv - mu * mu;
        rstd = rsqrtf(var + 1e-5f);
      }

      if (inr < S_INNER) {
        // ---- phase B (all threads): LN -> h, publish packed pairs
        {
          float h = fmaxf(fmaf((x - mu) * rstd, g_i, be_i), 0.f);
          float hn = dpp_mov<0xB1>(h);
          if (!(dim & 1)) h2cur[dim >> 1] = pkh((_Float16)h, (_Float16)hn);
        }
        __syncthreads();                                 // B2
        // ---- phase C (all threads): dots for rows g (and g+32)
        {
          const unsigned* hp = h2cur + 4 * dj;
          uint4 v0 = *(const uint4*)(hp + 0);
          uint4 v1 = *(const uint4*)(hp + 64);
          uint4 v2 = *(const uint4*)(hp + 128);
          uint4 v3 = *(const uint4*)(hp + 192);
          float a0 = 0.f, a1 = 0.f, a2 = 0.f, a3 = 0.f;
          a0 = fdot2u(hA0.x, v0.x, a0); a1 = fdot2u(hA0.y, v0.y, a1);
          a2 = fdot2u(hA0.z, v0.z, a2); a3 = fdot2u(hA0.w, v0.w, a3);
          a0 = fdot2u(hA1.x, v1.x, a0); a1 = fdot2u(hA1.y, v1.y, a1);
          a2 = fdot2u(hA1.z, v1.z, a2); a3 = fdot2u(hA1.w, v1.w, a3);
          a0 = fdot2u(hA2.x, v2.x, a0); a1 = fdot2u(hA2.y, v2.y, a1);
          a2 = fdot2u(hA2.z, v2.z, a2); a3 = fdot2u(hA2.w, v2.w, a3);
          a0 = fdot2u(hA3.x, v3.x, a0); a1 = fdot2u(hA3.y, v3.y, a1);
          a2 = fdot2u(hA3.z, v3.z, a2); a3 = fdot2u(hA3.w, v3.w, a3);
          float pA = row16_sum((a0 + a1) + (a2 + a3));
          float pB = 0.f;
          if (g16) {
            float e0 = 0.f, e1 = 0.f, e2 = 0.f, e3 = 0.f;
            e0 = fdot2u(hB0.x, v0.x, e0); e1 = fdot2u(hB0.y, v0.y, e1);
            e2 = fdot2u(hB0.z, v0.z, e2); e3 = fdot2u(hB0.w, v0.w, e3);
            e0 = fdot2u(hB1.x, v1.x, e0); e1 = fdot2u(hB1.y, v1.y, e1);
            e2 = fdot2u(hB1.z, v1.z, e2); e3 = fdot2u(hB1.w, v1.w, e3);
            e0 = fdot2u(hB2.x, v2.x, e0); e1 = fdot2u(hB2.y, v2.y, e1);
            e2 = fdot2u(hB2.z, v2.z, e2); e3 = fdot2u(hB2.w, v2.w, e3);
            e0 = fdot2u(hB3.x, v3.x, e0); e1 = fdot2u(hB3.y, v3.y, e1);
            e2 = fdot2u(hB3.z, v3.z, e2); e3 = fdot2u(hB3.w, v3.w, e3);
            pB = row16_sum((e0 + e1) + (e2 + e3));
          }
          if (dj == 0) {
            float ccA = (g < t) ? pA * lampow[t - 1 - g] : 0.f;
            _Float16 chA = (_Float16)ccA;
            ((unsigned short*)cbufh2)[g] = __builtin_bit_cast(unsigned short, chA);
            if (g16) {
              int rB = 32 + g;
              float ccB = (rB < t) ? pB * lampow[t - 1 - rB] : 0.f;
              _Float16 chB = (_Float16)ccB;
              ((unsigned short*)cbufh2)[rB] = __builtin_bit_cast(unsigned short, chB);
            }
          }
        }
        __syncthreads();                                 // B3
      } else {
        // ---- final inner: materialize h, append history, per-wave active list
        {
          float h = fmaxf(fmaf((x - mu) * rstd, g_i, be_i), 0.f);
          unsigned hb = (unsigned)__builtin_bit_cast(unsigned short, (_Float16)h);
          float hn = dpp_mov<0xB1>(h);
          if (!(dim & 1))
            histd[t * HDSTRIDE + (dim >> 1)] = pkh((_Float16)h, (_Float16)hn);
          switch (t) {
            HCASE(0)  HCASE(1)  HCASE(2)  HCASE(3)  HCASE(4)  HCASE(5)
            HCASE(6)  HCASE(7)  HCASE(8)  HCASE(9)  HCASE(10) HCASE(11)
            HCASE(12) HCASE(13) HCASE(14) HCASE(15) HCASE(16) HCASE(17)
            HCASE(18) HCASE(19) HCASE(20) HCASE(21) HCASE(22) HCASE(23)
          }
          if (t == T_STEPS - 1) hcur[dim] = h;
          unsigned long long mb = __ballot(h != 0.f);
          int myoff = __popcll(mb & ((1ull << lane) - 1ull));
          int wc  = __popcll(mb);
          int wcp = (wc + 1) & ~1;
          if (h != 0.f) {
            _Float16 hh = (_Float16)h;
            uint2 ent; ent.x = (unsigned)(dim << 10); ent.y = pkh(hh, hh);
            APr[wv * 64 + myoff] = ent;
          } else {
            int inact = lane - myoff;
            if (inact < wcp - wc) {
              uint2 zz; zz.x = 0u; zz.y = 0u;
              APr[wv * 64 + wc + inact] = zz;
            }
          }
          if (lane == 0) wcntp[wv] = wcp;
        }
        __syncthreads();                                 // B3f
      }
    }
  }

  // ---- epilogue: pred = h @ W_head^T + b_head, then loss/acc
  for (int r = wv; r < DG; r += 8) {
    const float4* w4  = (const float4*)(W_head + (size_t)r * DH);
    const float4* hc4 = (const float4*)hcur;
    float4 a4 = w4[lane];      float4 c4 = hc4[lane];
    float4 a5 = w4[lane + 64]; float4 c5 = hc4[lane + 64];
    float pdot = a4.x * c4.x + a4.y * c4.y + a4.z * c4.z + a4.w * c4.w
               + a5.x * c5.x + a5.y * c5.y + a5.z * c5.z + a5.w * c5.w;
    pdot = wave64_sum63(pdot);
    if (lane == 63) pred[r] = pdot + b_head[r];
  }
  __syncthreads();

  float sq = 0.f, pc = 0.f, pp = 0.f, cc = 0.f;
  if (tid < DG) {
    float pv = pred[tid];
    float cv = clean[(size_t)b * DG + tid];
    float d = pv - cv;
    sq = d * d; pc = pv * cv; pp = pv * pv; cc = cv * cv;
  }
  #pragma unroll
  for (int off = 32; off > 0; off >>= 1) {
    sq += __shfl_xor(sq, off, 64);
    pc += __shfl_xor(pc, off, 64);
    pp += __shfl_xor(pp, off, 64);
    cc += __shfl_xor(cc, off, 64);
  }
  if (lane == 0) {
    red4[wv * 4 + 0] = sq; red4[wv * 4 + 1] = pc;
    red4[wv * 4 + 2] = pp; red4[wv * 4 + 3] = cc;
  }
  __syncthreads();
  if (tid == 0) {
    float Sq = 0.f, Pc = 0.f, Pp = 0.f, Cc = 0.f;
    #pragma unroll
    for (int w = 0; w < 8; ++w) {
      Sq += red4[w * 4 + 0]; Pc += red4[w * 4 + 1];
      Pp += red4[w * 4 + 2]; Cc += red4[w * 4 + 3];
    }
    outbuf[b]         = Sq / (Cc + 1e-6f);
    outbuf[BATCH + b] = Pc / ((sqrtf(Pp) + 1e-6f) * (sqrtf(Cc) + 1e-6f));
  }
}

__global__ __launch_bounds__(64)
void finalize_k(const float* __restrict__ outbuf, float* __restrict__ out) {
  int tid = threadIdx.x;
  float l = (tid < BATCH) ? outbuf[tid] : 0.f;
  float a = (tid < BATCH) ? outbuf[BATCH + tid] : 0.f;
  #pragma unroll
  for (int off = 32; off > 0; off >>= 1) {
    l += __shfl_xor(l, off, 64);
    a += __shfl_xor(a, off, 64);
  }
  if (tid == 0) {
    out[0] = l * (1.f / (float)BATCH);
    out[1] = a * (1.f / (float)BATCH);
  }
}

extern "C" void kernel_launch(void* const* d_in, const int* in_sizes, int n_in,
                              void* d_out, int out_size, void* d_ws, size_t ws_size,
                              hipStream_t stream) {
  (void)in_sizes; (void)n_in; (void)out_size; (void)ws_size;
  const float* z      = (const float*)d_in[0];
  const float* clean  = (const float*)d_in[1];
  const float* W_h    = (const float*)d_in[2];
  const float* W_g    = (const float*)d_in[3];
  const float* b_h    = (const float*)d_in[4];
  const float* gamma  = (const float*)d_in[5];
  const float* beta   = (const float*)d_in[6];
  const float* W_head = (const float*)d_in[7];
  const float* b_head = (const float*)d_in[8];

  float* wsf     = (float*)d_ws;
  uint2* Whq     = (uint2*)wsf;                           // 65536 uint2
  float* WgT     = wsf + 131072;                          // 256*512
  float* ZG      = WgT + (size_t)DG * DH;                 // 2304*512
  float* outbuf  = ZG + (size_t)T_STEPS * BATCH * DH;     // 96

  hipLaunchKernelGGL(pack_whq, dim3(256), dim3(256), 0, stream, W_h, Whq);
  hipLaunchKernelGGL(transpose_k, dim3(DG / 32, DH / 32), dim3(256), 0, stream,
                     W_g, WgT, DH, DG);
  hipLaunchKernelGGL(zg_kernel, dim3((T_STEPS * BATCH) / 8), dim3(DH), 0, stream,
                     z, WgT, ZG);
  hipLaunchKernelGGL(rnn_main, dim3(BATCH), dim3(512), 0, stream,
                     ZG, Whq, b_h, gamma, beta, W_head, b_head, clean, outbuf);
  hipLaunchKernelGGL(finalize_k, dim3(1), dim3(64), 0, stream,
                     outbuf, (float*)d_out);
}

// Round 10
// 278.095 us; speedup vs baseline: 1.9091x; 1.0305x over previous
//
#include <hip/hip_runtime.h>

#define T_STEPS 48
#define BATCH   48
#define DG      256
#define DH      512
#define S_INNER 3
#define HDSTRIDE 260   // histd row stride in u32: +4-bank skew per row, 16B-aligned

typedef _Float16 hf2 __attribute__((ext_vector_type(2)));

__device__ __forceinline__ hf2 bch(unsigned u) { return __builtin_bit_cast(hf2, u); }
__device__ __forceinline__ unsigned pkh(_Float16 a, _Float16 b) {
  hf2 v{a, b}; return __builtin_bit_cast(unsigned, v);
}
__device__ __forceinline__ float fdot2u(unsigned a, unsigned b, float c) {
#if __has_builtin(__builtin_amdgcn_fdot2)
  return __builtin_amdgcn_fdot2(bch(a), bch(b), c, false);
#else
  hf2 x = bch(a), y = bch(b);
  return fmaf((float)x.x, (float)y.x, fmaf((float)x.y, (float)y.y, c));
#endif
}
template <int CTRL>
__device__ __forceinline__ float dpp_add(float v) {
  int t = __builtin_amdgcn_update_dpp(0, __float_as_int(v), CTRL, 0xf, 0xf, true);
  return v + __int_as_float(t);
}
template <int CTRL>
__device__ __forceinline__ float dpp_mov(float v) {
  return __int_as_float(
      __builtin_amdgcn_update_dpp(0, __float_as_int(v), CTRL, 0xf, 0xf, true));
}
// 64-lane sum, result valid in lane 63; zero LDS traffic
__device__ __forceinline__ float wave64_sum63(float v) {
  v = dpp_add<0xB1>(v);    // xor1 (quad_perm)
  v = dpp_add<0x4E>(v);    // xor2 (quad_perm)
  v = dpp_add<0x141>(v);   // row_half_mirror
  v = dpp_add<0x140>(v);   // row_mirror
  v = dpp_add<0x142>(v);   // row_bcast15
  v = dpp_add<0x143>(v);   // row_bcast31 -> total in lane 63
  return v;
}
// sum over each 16-lane row, result in all 16 lanes of the row
__device__ __forceinline__ float row16_sum(float v) {
  v = dpp_add<0xB1>(v);
  v = dpp_add<0x4E>(v);
  v = dpp_add<0x141>(v);
  v = dpp_add<0x140>(v);
  return v;
}

// ---------- weight packing: Whq[j*128 + q] = 4 dims {4q..4q+3} of column j, fp16
__global__ __launch_bounds__(256)
void pack_whq(const float* __restrict__ W, uint2* __restrict__ Wq) {
  int idx = blockIdx.x * 256 + threadIdx.x;   // 65536
  int j = idx & (DH - 1), q = idx >> 9;
  float w0 = W[(size_t)(4 * q + 0) * DH + j];
  float w1 = W[(size_t)(4 * q + 1) * DH + j];
  float w2 = W[(size_t)(4 * q + 2) * DH + j];
  float w3 = W[(size_t)(4 * q + 3) * DH + j];
  uint2 o;
  o.x = pkh((_Float16)w0, (_Float16)w1);
  o.y = pkh((_Float16)w2, (_Float16)w3);
  Wq[(size_t)j * 128 + q] = o;
}

__global__ __launch_bounds__(256)
void transpose_k(const float* __restrict__ in, float* __restrict__ out, int R, int C) {
  __shared__ float tile[32][33];
  int c0 = blockIdx.x * 32, r0 = blockIdx.y * 32;
  int tx = threadIdx.x & 31, ty = threadIdx.x >> 5;
  #pragma unroll
  for (int k = 0; k < 32; k += 8)
    tile[ty + k][tx] = in[(size_t)(r0 + ty + k) * C + (c0 + tx)];
  __syncthreads();
  #pragma unroll
  for (int k = 0; k < 32; k += 8)
    out[(size_t)(c0 + ty + k) * R + (r0 + tx)] = tile[tx][ty + k];
}

__global__ __launch_bounds__(DH, 2)
void zg_kernel(const float* __restrict__ z, const float* __restrict__ WgT,
               float* __restrict__ ZG) {
  const int row0 = blockIdx.x * 8;
  const int tid = threadIdx.x;
  __shared__ __align__(16) float zl[8][DG];
  for (int i = tid; i < 8 * (DG / 4); i += DH) {
    int r = i >> 6, c = i & 63;
    ((float4*)zl[r])[c] = ((const float4*)(z + (size_t)(row0 + r) * DG))[c];
  }
  __syncthreads();
  float acc[8] = {0.f, 0.f, 0.f, 0.f, 0.f, 0.f, 0.f, 0.f};
  for (int j = 0; j < DG; j += 4) {
    float w0 = WgT[(size_t)(j + 0) * DH + tid];
    float w1 = WgT[(size_t)(j + 1) * DH + tid];
    float w2 = WgT[(size_t)(j + 2) * DH + tid];
    float w3 = WgT[(size_t)(j + 3) * DH + tid];
    #pragma unroll
    for (int r = 0; r < 8; ++r) {
      float4 zz = ((const float4*)zl[r])[j >> 2];
      acc[r] = fmaf(w0, zz.x, acc[r]);
      acc[r] = fmaf(w1, zz.y, acc[r]);
      acc[r] = fmaf(w2, zz.z, acc[r]);
      acc[r] = fmaf(w3, zz.w, acc[r]);
    }
  }
  #pragma unroll
  for (int r = 0; r < 8; ++r)
    ZG[(size_t)(row0 + r) * DH + tid] = acc[r];
}

#define HCASE(s) case (2*(s)): hreg[(s)] = hb; break; \
                 case (2*(s)+1): hreg[(s)] |= (hb << 16); break;

#define MVACC(E, wA, wB) do {                                        \
    hf2 h0 = bch((E).y), h1 = bch((E).w);                            \
    a0 += bch((wA).x) * h0; a1 += bch((wA).y) * h0;                  \
    a2 += bch((wA).z) * h0; a3 += bch((wA).w) * h0;                  \
    b0 += bch((wB).x) * h1; b1 += bch((wB).y) * h1;                  \
    b2 += bch((wB).z) * h1; b3 += bch((wB).w) * h1;                  \
  } while (0)

#define LDW(off) (*(const uint4*)(Wb + ((off) + l16)))

__global__ __launch_bounds__(512, 2)
void rnn_main(const float* __restrict__ ZG, const uint2* __restrict__ Whq,
              const float* __restrict__ bh, const float* __restrict__ gamma,
              const float* __restrict__ beta, const float* __restrict__ W_head,
              const float* __restrict__ b_head, const float* __restrict__ clean,
              float* __restrict__ outbuf) {
  const int b = blockIdx.x;
  const int tid  = threadIdx.x;         // 512 threads = 8 waves
  const int lane = tid & 63;
  const int wv   = tid >> 6;            // wave = matvec slice = active region
  const int dim  = tid;                 // owner dim (all threads own a dim)
  const int g    = tid >> 4;            // dot group 0..31 (row g; +row g+32 if g<16)
  const int dj   = tid & 15;            // chunk id within row
  const bool g16 = tid < 256;           // wave-uniform: groups 0..15 take 2 rows

  __shared__ __align__(16) unsigned histd[T_STEPS * HDSTRIDE];  // fp16 dim-pair history
  __shared__ __align__(16) float    pm[8 * DH];                 // per-slice partials
  __shared__ __align__(16) uint2    APr[8 * 64];                // per-wave-region actives
  __shared__ __align__(16) unsigned h2cur[256];                 // current h, dim-pairs
  __shared__ __align__(16) unsigned cbufh2[24];                 // c coeffs (48 fp16)
  __shared__ __align__(16) float    hcur[DH];
  __shared__ __align__(16) float    pred[DG];
  __shared__ __align__(16) float2   red[8];
  __shared__ float  red4[32];
  __shared__ int    wcntp[8];
  __shared__ float  lampow[T_STEPS];

  const float g_i  = gamma[dim];
  const float be_i = beta[dim];
  const float bh_i = bh[dim];
  if (tid == 0) {
    float pw = 0.5f;                    // eta folded in
    for (int k = 0; k < T_STEPS; ++k) { lampow[k] = pw; pw *= 0.95f; }
  }
  unsigned hreg[24];                    // owner's fp16 history column, s-pairs
  #pragma unroll
  for (int k = 0; k < 24; ++k) hreg[k] = 0u;

  const char* Wb = (const char*)Whq;    // SGPR base for saddr-form gathers
  const unsigned l16 = (unsigned)(lane << 4);
  __syncthreads();

  for (int t = 0; t < T_STEPS; ++t) {
    float zg = ZG[((size_t)t * BATCH + b) * DH + dim];

    // per-step prefetch (gated by row < t): chunks {4*dj + 64k} of dot rows
    uint4 hA0, hA1, hA2, hA3, hB0, hB1, hB2, hB3;
    hA0 = hA1 = hA2 = hA3 = make_uint4(0u, 0u, 0u, 0u);
    hB0 = hB1 = hB2 = hB3 = make_uint4(0u, 0u, 0u, 0u);
    if (g < t) {
      const unsigned* rpA = histd + g * HDSTRIDE + 4 * dj;
      hA0 = *(const uint4*)(rpA + 0);
      hA1 = *(const uint4*)(rpA + 64);
      hA2 = *(const uint4*)(rpA + 128);
      hA3 = *(const uint4*)(rpA + 192);
    }
    if (g16 && 32 + g < t) {
      const unsigned* rpB = histd + (32 + g) * HDSTRIDE + 4 * dj;
      hB0 = *(const uint4*)(rpB + 0);
      hB1 = *(const uint4*)(rpB + 64);
      hB2 = *(const uint4*)(rpB + 128);
      hB3 = *(const uint4*)(rpB + 192);
    }

    // ---- matvec: wave wv handles region wv; lane covers dims 8*lane..8*lane+7
    //      4-deep software pipeline (8 loads in flight/lane)
    {
      hf2 a0{}, a1{}, a2{}, a3{}, b0{}, b1{}, b2{}, b3{};
      if (t > 0) {
        const int n = wcntp[wv];        // multiple of 8 (or 0), uniform in wave
        if (n > 0) {
          const uint4* ap4 = (const uint4*)(APr + wv * 64);  // entry pairs
          const int G = n >> 1;          // multiple of 4, >= 4
          uint4 E0 = ap4[0], E1 = ap4[1], E2 = ap4[2], E3 = ap4[3];
          uint4 wA0 = LDW(E0.x), wB0 = LDW(E0.z);
          uint4 wA1 = LDW(E1.x), wB1 = LDW(E1.z);
          uint4 wA2 = LDW(E2.x), wB2 = LDW(E2.z);
          uint4 wA3 = LDW(E3.x), wB3 = LDW(E3.z);
          for (int grp = 4; grp < G; grp += 4) {
            uint4 F0 = ap4[grp], F1 = ap4[grp + 1];
            uint4 F2 = ap4[grp + 2], F3 = ap4[grp + 3];
            uint4 xA0 = LDW(F0.x), xB0 = LDW(F0.z);
            uint4 xA1 = LDW(F1.x), xB1 = LDW(F1.z);
            uint4 xA2 = LDW(F2.x), xB2 = LDW(F2.z);
            uint4 xA3 = LDW(F3.x), xB3 = LDW(F3.z);
            MVACC(E0, wA0, wB0); MVACC(E1, wA1, wB1);
            MVACC(E2, wA2, wB2); MVACC(E3, wA3, wB3);
            E0 = F0; E1 = F1; E2 = F2; E3 = F3;
            wA0 = xA0; wB0 = xB0; wA1 = xA1; wB1 = xB1;
            wA2 = xA2; wB2 = xB2; wA3 = xA3; wB3 = xB3;
          }
          MVACC(E0, wA0, wB0); MVACC(E1, wA1, wB1);
          MVACC(E2, wA2, wB2); MVACC(E3, wA3, wB3);
        }
      }
      float4 s0, s1;
      s0.x = (float)a0.x + (float)b0.x; s0.y = (float)a0.y + (float)b0.y;
      s0.z = (float)a1.x + (float)b1.x; s0.w = (float)a1.y + (float)b1.y;
      s1.x = (float)a2.x + (float)b2.x; s1.y = (float)a2.y + (float)b2.y;
      s1.z = (float)a3.x + (float)b3.x; s1.w = (float)a3.y + (float)b3.y;
      float4* pmw = (float4*)(pm + wv * DH);
      pmw[2 * lane + 0] = s0;
      pmw[2 * lane + 1] = s1;
    }
    __syncthreads();                                     // B0

    float base_i = bh_i + zg;
    if (t > 0) {
      float ps = 0.f;
      #pragma unroll
      for (int sl = 0; sl < 8; ++sl) ps += pm[sl * DH + dim];
      base_i += ps;
    }

    for (int inr = 0; inr <= S_INNER; ++inr) {
      // ---- phase A (all threads): x = base + Ah; DPP sums; lane63 publishes
      float x;
      {
        float Ah = 0.f;
        if (inr > 0 && t > 0) {
          const uint4* cbp = (const uint4*)cbufh2;
          float A0 = 0.f, A1 = 0.f, A2 = 0.f, A3 = 0.f;
          {
            uint4 c = cbp[0];
            A0 = fdot2u(hreg[0], c.x, A0); A1 = fdot2u(hreg[1], c.y, A1);
            A2 = fdot2u(hreg[2], c.z, A2); A3 = fdot2u(hreg[3], c.w, A3);
          }
          if (t > 8) {
            uint4 c = cbp[1];
            A0 = fdot2u(hreg[4], c.x, A0); A1 = fdot2u(hreg[5], c.y, A1);
            A2 = fdot2u(hreg[6], c.z, A2); A3 = fdot2u(hreg[7], c.w, A3);
          }
          if (t > 16) {
            uint4 c = cbp[2];
            A0 = fdot2u(hreg[8], c.x, A0);  A1 = fdot2u(hreg[9], c.y, A1);
            A2 = fdot2u(hreg[10], c.z, A2); A3 = fdot2u(hreg[11], c.w, A3);
          }
          if (t > 24) {
            uint4 c = cbp[3];
            A0 = fdot2u(hreg[12], c.x, A0); A1 = fdot2u(hreg[13], c.y, A1);
            A2 = fdot2u(hreg[14], c.z, A2); A3 = fdot2u(hreg[15], c.w, A3);
          }
          if (t > 32) {
            uint4 c = cbp[4];
            A0 = fdot2u(hreg[16], c.x, A0); A1 = fdot2u(hreg[17], c.y, A1);
            A2 = fdot2u(hreg[18], c.z, A2); A3 = fdot2u(hreg[19], c.w, A3);
          }
          if (t > 40) {
            uint4 c = cbp[5];
            A0 = fdot2u(hreg[20], c.x, A0); A1 = fdot2u(hreg[21], c.y, A1);
            A2 = fdot2u(hreg[22], c.z, A2); A3 = fdot2u(hreg[23], c.w, A3);
          }
          Ah = (A0 + A1) + (A2 + A3);
        }
        x = base_i + Ah;
        float sa = wave64_sum63(x);
        float sb = wave64_sum63(x * x);
        if (lane == 63) red[wv] = make_float2(sa, sb);
      }
      __syncthreads();                                   // B1
      float mu, rstd;
      {
        const float4* rr = (const float4*)red;
        float4 r0 = rr[0], r1 = rr[1], r2 = rr[2], r3 = rr[3];
        float s  = ((r0.x + r1.x) + (r2.x + r3.x)) + ((r0.z + r1.z) + (r2.z + r3.z));
        float s2 = ((r0.y + r1.y) + (r2.y + r3.y)) + ((r0.w + r1.w) + (r2.w + r3.w));
        const float inv = 1.f / (float)DH;
        mu = s * inv;
        float var = s2 * inv - mu * mu;
        rstd = rsqrtf(var + 1e-5f);
      }

      if (inr < S_INNER) {
        // ---- phase B (all threads): LN -> h, publish packed pairs
        {
          float h = fmaxf(fmaf((x - mu) * rstd, g_i, be_i), 0.f);
          float hn = dpp_mov<0xB1>(h);
          if (!(dim & 1)) h2cur[dim >> 1] = pkh((_Float16)h, (_Float16)hn);
        }
        __syncthreads();                                 // B2
        // ---- phase C: dots for rows g (and g+32), gated by row < t
        {
          float pA = 0.f, pB = 0.f;
          if (g < t) {
            const unsigned* hp = h2cur + 4 * dj;
            uint4 v0 = *(const uint4*)(hp + 0);
            uint4 v1 = *(const uint4*)(hp + 64);
            uint4 v2 = *(const uint4*)(hp + 128);
            uint4 v3 = *(const uint4*)(hp + 192);
            float a0 = 0.f, a1 = 0.f, a2 = 0.f, a3 = 0.f;
            a0 = fdot2u(hA0.x, v0.x, a0); a1 = fdot2u(hA0.y, v0.y, a1);
            a2 = fdot2u(hA0.z, v0.z, a2); a3 = fdot2u(hA0.w, v0.w, a3);
            a0 = fdot2u(hA1.x, v1.x, a0); a1 = fdot2u(hA1.y, v1.y, a1);
            a2 = fdot2u(hA1.z, v1.z, a2); a3 = fdot2u(hA1.w, v1.w, a3);
            a0 = fdot2u(hA2.x, v2.x, a0); a1 = fdot2u(hA2.y, v2.y, a1);
            a2 = fdot2u(hA2.z, v2.z, a2); a3 = fdot2u(hA2.w, v2.w, a3);
            a0 = fdot2u(hA3.x, v3.x, a0); a1 = fdot2u(hA3.y, v3.y, a1);
            a2 = fdot2u(hA3.z, v3.z, a2); a3 = fdot2u(hA3.w, v3.w, a3);
            pA = row16_sum((a0 + a1) + (a2 + a3));
            if (g16 && 32 + g < t) {
              float e0 = 0.f, e1 = 0.f, e2 = 0.f, e3 = 0.f;
              e0 = fdot2u(hB0.x, v0.x, e0); e1 = fdot2u(hB0.y, v0.y, e1);
              e2 = fdot2u(hB0.z, v0.z, e2); e3 = fdot2u(hB0.w, v0.w, e3);
              e0 = fdot2u(hB1.x, v1.x, e0); e1 = fdot2u(hB1.y, v1.y, e1);
              e2 = fdot2u(hB1.z, v1.z, e2); e3 = fdot2u(hB1.w, v1.w, e3);
              e0 = fdot2u(hB2.x, v2.x, e0); e1 = fdot2u(hB2.y, v2.y, e1);
              e2 = fdot2u(hB2.z, v2.z, e2); e3 = fdot2u(hB2.w, v2.w, e3);
              e0 = fdot2u(hB3.x, v3.x, e0); e1 = fdot2u(hB3.y, v3.y, e1);
              e2 = fdot2u(hB3.z, v3.z, e2); e3 = fdot2u(hB3.w, v3.w, e3);
              pB = row16_sum((e0 + e1) + (e2 + e3));
            }
          }
          if (dj == 0) {
            float ccA = (g < t) ? pA * lampow[t - 1 - g] : 0.f;
            _Float16 chA = (_Float16)ccA;
            ((unsigned short*)cbufh2)[g] = __builtin_bit_cast(unsigned short, chA);
            if (g16) {
              int rB = 32 + g;
              float ccB = (rB < t) ? pB * lampow[t - 1 - rB] : 0.f;
              _Float16 chB = (_Float16)ccB;
              ((unsigned short*)cbufh2)[rB] = __builtin_bit_cast(unsigned short, chB);
            }
          }
        }
        __syncthreads();                                 // B3
      } else {
        // ---- final inner: materialize h, append history, per-wave active list
        {
          float h = fmaxf(fmaf((x - mu) * rstd, g_i, be_i), 0.f);
          unsigned hb = (unsigned)__builtin_bit_cast(unsigned short, (_Float16)h);
          float hn = dpp_mov<0xB1>(h);
          if (!(dim & 1))
            histd[t * HDSTRIDE + (dim >> 1)] = pkh((_Float16)h, (_Float16)hn);
          switch (t) {
            HCASE(0)  HCASE(1)  HCASE(2)  HCASE(3)  HCASE(4)  HCASE(5)
            HCASE(6)  HCASE(7)  HCASE(8)  HCASE(9)  HCASE(10) HCASE(11)
            HCASE(12) HCASE(13) HCASE(14) HCASE(15) HCASE(16) HCASE(17)
            HCASE(18) HCASE(19) HCASE(20) HCASE(21) HCASE(22) HCASE(23)
          }
          if (t == T_STEPS - 1) hcur[dim] = h;
          unsigned long long mb = __ballot(h != 0.f);
          int myoff = __popcll(mb & ((1ull << lane) - 1ull));
          int wc  = __popcll(mb);
          int wcp = (wc + 7) & ~7;      // pad to multiple of 8 entries
          if (h != 0.f) {
            _Float16 hh = (_Float16)h;
            uint2 ent; ent.x = (unsigned)(dim << 10); ent.y = pkh(hh, hh);
            APr[wv * 64 + myoff] = ent;
          } else {
            int inact = lane - myoff;
            if (inact < wcp - wc) {
              uint2 zz; zz.x = 0u; zz.y = 0u;
              APr[wv * 64 + wc + inact] = zz;
            }
          }
          if (lane == 0) wcntp[wv] = wcp;
        }
        __syncthreads();                                 // B3f
      }
    }
  }

  // ---- epilogue: pred = h @ W_head^T + b_head, then loss/acc
  for (int r = wv; r < DG; r += 8) {
    const float4* w4  = (const float4*)(W_head + (size_t)r * DH);
    const float4* hc4 = (const float4*)hcur;
    float4 a4 = w4[lane];      float4 c4 = hc4[lane];
    float4 a5 = w4[lane + 64]; float4 c5 = hc4[lane + 64];
    float pdot = a4.x * c4.x + a4.y * c4.y + a4.z * c4.z + a4.w * c4.w
               + a5.x * c5.x + a5.y * c5.y + a5.z * c5.z + a5.w * c5.w;
    pdot = wave64_sum63(pdot);
    if (lane == 63) pred[r] = pdot + b_head[r];
  }
  __syncthreads();

  float sq = 0.f, pc = 0.f, pp = 0.f, cc = 0.f;
  if (tid < DG) {
    float pv = pred[tid];
    float cv = clean[(size_t)b * DG + tid];
    float d = pv - cv;
    sq = d * d; pc = pv * cv; pp = pv * pv; cc = cv * cv;
  }
  #pragma unroll
  for (int off = 32; off > 0; off >>= 1) {
    sq += __shfl_xor(sq, off, 64);
    pc += __shfl_xor(pc, off, 64);
    pp += __shfl_xor(pp, off, 64);
    cc += __shfl_xor(cc, off, 64);
  }
  if (lane == 0) {
    red4[wv * 4 + 0] = sq; red4[wv * 4 + 1] = pc;
    red4[wv * 4 + 2] = pp; red4[wv * 4 + 3] = cc;
  }
  __syncthreads();
  if (tid == 0) {
    float Sq = 0.f, Pc = 0.f, Pp = 0.f, Cc = 0.f;
    #pragma unroll
    for (int w = 0; w < 8; ++w) {
      Sq += red4[w * 4 + 0]; Pc += red4[w * 4 + 1];
      Pp += red4[w * 4 + 2]; Cc += red4[w * 4 + 3];
    }
    outbuf[b]         = Sq / (Cc + 1e-6f);
    outbuf[BATCH + b] = Pc / ((sqrtf(Pp) + 1e-6f) * (sqrtf(Cc) + 1e-6f));
  }
}

__global__ __launch_bounds__(64)
void finalize_k(const float* __restrict__ outbuf, float* __restrict__ out) {
  int tid = threadIdx.x;
  float l = (tid < BATCH) ? outbuf[tid] : 0.f;
  float a = (tid < BATCH) ? outbuf[BATCH + tid] : 0.f;
  #pragma unroll
  for (int off = 32; off > 0; off >>= 1) {
    l += __shfl_xor(l, off, 64);
    a += __shfl_xor(a, off, 64);
  }
  if (tid == 0) {
    out[0] = l * (1.f / (float)BATCH);
    out[1] = a * (1.f / (float)BATCH);
  }
}

extern "C" void kernel_launch(void* const* d_in, const int* in_sizes, int n_in,
                              void* d_out, int out_size, void* d_ws, size_t ws_size,
                              hipStream_t stream) {
  (void)in_sizes; (void)n_in; (void)out_size; (void)ws_size;
  const float* z      = (const float*)d_in[0];
  const float* clean  = (const float*)d_in[1];
  const float* W_h    = (const float*)d_in[2];
  const float* W_g    = (const float*)d_in[3];
  const float* b_h    = (const float*)d_in[4];
  const float* gamma  = (const float*)d_in[5];
  const float* beta   = (const float*)d_in[6];
  const float* W_head = (const float*)d_in[7];
  const float* b_head = (const float*)d_in[8];

  float* wsf     = (float*)d_ws;
  uint2* Whq     = (uint2*)wsf;                           // 65536 uint2
  float* WgT     = wsf + 131072;                          // 256*512
  float* ZG      = WgT + (size_t)DG * DH;                 // 2304*512
  float* outbuf  = ZG + (size_t)T_STEPS * BATCH * DH;     // 96

  hipLaunchKernelGGL(pack_whq, dim3(256), dim3(256), 0, stream, W_h, Whq);
  hipLaunchKernelGGL(transpose_k, dim3(DG / 32, DH / 32), dim3(256), 0, stream,
                     W_g, WgT, DH, DG);
  hipLaunchKernelGGL(zg_kernel, dim3((T_STEPS * BATCH) / 8), dim3(DH), 0, stream,
                     z, WgT, ZG);
  hipLaunchKernelGGL(rnn_main, dim3(BATCH), dim3(512), 0, stream,
                     ZG, Whq, b_h, gamma, beta, W_head, b_head, clean, outbuf);
  hipLaunchKernelGGL(finalize_k, dim3(1), dim3(64), 0, stream,
                     outbuf, (float*)d_out);
}